// Round 2
// baseline (18298.795 us; speedup 1.0000x reference)
//
#include <hip/hip_runtime.h>
#include <hip/hip_bf16.h>
#include <math.h>

// FNO2d: B=8, S=192, pad->201x201, C=64, modes 12x12 (ky in {0..11,189..200}), 4 layers.
// Partial-DFT formulation + Gram-matrix GroupNorm stats (no bypass/head buffers).
// Activations stored bf16; total workspace ~91 MB.

#define NN 201
#define SS 192
#define NPIX 40401      // 201*201
#define QPIX 36864      // 192*192
#define BB 8
#define PI_F 3.14159265358979323846f

typedef __hip_bfloat16 bf16;

__device__ __forceinline__ float gelu_f(float x){
  return 0.5f*x*(1.0f+erff(x*0.7071067811865476f));
}
__device__ __forceinline__ float b2f(bf16 v){ return __bfloat162float(v); }
__device__ __forceinline__ bf16  f2b(float v){ return __float2bfloat16(v); }

// tab[k][n][0]=cos(2*pi*k*n/201), [1]=sin, k=0..12, n=0..200 (k*n reduced mod 201 exactly)
__global__ void k_tab(float* __restrict__ tab){
  int t = blockIdx.x*blockDim.x+threadIdx.x;
  if(t>=13*NN) return;
  int k=t/NN, n=t-k*NN;
  int m=(k*n)%NN;
  float ang = (2.0f*PI_F/201.0f)*(float)m;
  tab[2*t]   = cosf(ang);
  tab[2*t+1] = sinf(ang);
}

// h0[b][c][p] = (feat(43) @ Wp)[c] + bp[c]; zero in pad region. bf16 out.
__global__ void k_encoder(const float* __restrict__ x, const float* __restrict__ Wp,
                          const float* __restrict__ bp, bf16* __restrict__ A){
  int tid=threadIdx.x;
  int p = blockIdx.x*256+tid;
  if(p>=NPIX) return;
  int b = blockIdx.y;
  bf16* out = A + ((size_t)b*64)*NPIX + p;
  int hh=p/NN, ww=p-hh*NN;
  if(hh>=SS || ww>=SS){
    for(int o=0;o<64;o++) out[(size_t)o*NPIX]=f2b(0.0f);
    return;
  }
  float feat[43];
  float gx = (float)hh*(1.0f/191.0f);
  float gy = (float)ww*(1.0f/191.0f);
  feat[0]=x[((size_t)b*SS+hh)*SS+ww];
  feat[1]=gx; feat[2]=gy;
  #pragma unroll
  for(int l=0;l<10;l++){
    float f = PI_F*(float)(1<<l);
    float sxv,cxv,syv,cyv;
    sincosf(gx*f,&sxv,&cxv);
    sincosf(gy*f,&syv,&cyv);
    feat[3+2*l]=cxv;  feat[4+2*l]=cyv;
    feat[23+2*l]=sxv; feat[24+2*l]=syv;
  }
  for(int o=0;o<64;o+=2){
    float a0=bp[o], a1=bp[o+1];
    #pragma unroll
    for(int j=0;j<43;j++){ a0 += feat[j]*Wp[j*64+o]; a1 += feat[j]*Wp[j*64+o+1]; }
    out[(size_t)o*NPIX]=f2b(a0);
    out[(size_t)(o+1)*NPIX]=f2b(a1);
  }
}

// Forward DFT along W: XW[bc][h][kx][{re,im}] = sum_w A[bc][h][w] * e^{-i ang kx w}
__global__ void k_dftw(const bf16* __restrict__ A, const float* __restrict__ tab,
                       float* __restrict__ XW){
  __shared__ float st[12*NN*2];
  int tid=threadIdx.x;
  for(int i=tid;i<12*NN*2;i+=256) st[i]=tab[i];
  __syncthreads();
  int t=blockIdx.x*256+tid;
  int r=t/24;
  if(r>=512*NN) return;
  int q=t-r*24;
  int kx=q>>1, comp=q&1;
  const bf16* row = A + (size_t)r*NN;
  const float* tb = st + kx*NN*2 + comp;
  float s=0.0f;
  for(int w=0;w<NN;w++) s += b2f(row[w])*tb[2*w];
  XW[t] = comp ? -s : s;
}

// Forward DFT along H: XF[m][b][c][{re,im}], m=j*12+kx; j<12 -> ky=j (e^{-i}), j>=12 -> ky=177+j == e^{+i w (24-j) h}
__global__ void k_dfth(const float* __restrict__ XW, const float* __restrict__ tab,
                       float* __restrict__ XF){
  int t=blockIdx.x*256+threadIdx.x;
  if(t>=288*512) return;
  int m=t>>9;
  int bc=t&511;
  int j=m/12, kx=m-j*12;
  int k2 = (j<12)? j : 24-j;
  float sgn = (j<12)? -1.0f : 1.0f;
  const float* xw = XW + (size_t)bc*(NN*24) + kx*2;
  const float* tb = tab + k2*NN*2;
  float re=0.0f,im=0.0f;
  for(int h2=0;h2<NN;h2++){
    float a=xw[h2*24], b2=xw[h2*24+1];
    float c=tb[2*h2], s2=sgn*tb[2*h2+1];
    re += a*c - b2*s2;
    im += a*s2 + b2*c;
  }
  XF[2*t]=re; XF[2*t+1]=im;
}

// Per-mode 64x64 complex mix
__global__ void __launch_bounds__(512) k_modemix(const float* __restrict__ XF,
     const float* __restrict__ w1, const float* __restrict__ w2,
     float* __restrict__ XO){
  __shared__ float sx[1024];
  __shared__ float swr[4096], swi[4096];
  int m=blockIdx.x;
  int j=m/12, kx=m-j*12;
  int tid=threadIdx.x;
  sx[tid]     = XF[(size_t)m*1024+tid];
  sx[tid+512] = XF[(size_t)m*1024+tid+512];
  const float* wsrc = (j<12)? w1 : w2;
  int xi = (j<12)? j : j-12;
  size_t base=((size_t)xi*12+kx)*2;
  for(int io=tid;io<4096;io+=512){
    swr[io]=wsrc[(size_t)io*288+base];
    swi[io]=wsrc[(size_t)io*288+base+1];
  }
  __syncthreads();
  int b=tid>>6, o=tid&63;
  const float* xb = sx + b*128;
  float re=0.0f,im=0.0f;
  #pragma unroll 8
  for(int i=0;i<64;i++){
    float a=xb[2*i], b2=xb[2*i+1];
    float c=swr[i*64+o], d=swi[i*64+o];
    re += a*c - b2*d;
    im += a*d + b2*c;
  }
  XO[2*((size_t)m*512+tid)]  =re;
  XO[2*((size_t)m*512+tid)+1]=im;
}

// Inverse DFT along H: Y[bo][h][kx] = sum_j XO[j*12+kx][b][o] * e^{+i w ky_j h}
__global__ void k_idfth(const float* __restrict__ XO, const float* __restrict__ tab,
                        float* __restrict__ Y){
  int t=blockIdx.x*256+threadIdx.x;
  if(t>=512*NN*12) return;
  int kx=t%12;
  int rem=t/12;
  int h2=rem%NN;
  int bo=rem/NN;
  int b=bo>>6, o=bo&63;
  float re=0.0f,im=0.0f;
  #pragma unroll
  for(int j=0;j<24;j++){
    int k2=(j<12)?j:24-j;
    float sgn=(j<12)?1.0f:-1.0f;
    const float* xo = XO + 2*(((size_t)(j*12+kx)*8+b)*64+o);
    float a=xo[0], b2=xo[1];
    const float* tb=tab+ (k2*NN+h2)*2;
    float c=tb[0], s2=sgn*tb[1];
    re += a*c - b2*s2;
    im += a*s2 + b2*c;
  }
  Y[2*t]=re; Y[2*t+1]=im;
}

// Inverse C2R along W + 1/N^2. bf16 out.
__global__ void k_idftw(const float* __restrict__ Y, const float* __restrict__ tab,
                        bf16* __restrict__ C){
  __shared__ float st[12*NN*2];
  int tid=threadIdx.x;
  for(int i=tid;i<12*NN*2;i+=256) st[i]=tab[i];
  __syncthreads();
  int t=blockIdx.x*256+tid;
  int p=t%NPIX;
  int bo=t/NPIX;
  int h2=p/NN, w2=p-h2*NN;
  const float* y = Y + ((size_t)bo*NN+h2)*24;
  float acc=y[0];
  #pragma unroll
  for(int k=1;k<12;k++){
    acc += 2.0f*( y[2*k]*st[(k*NN+w2)*2] - y[2*k+1]*st[(k*NN+w2)*2+1] );
  }
  C[t]=f2b(acc*(1.0f/40401.0f));
}

// Per-batch Gram matrix G[b][64][64] = sum_p x_i x_j and column sums S[b][64].
// Region: HRxWR (padded: 201x201 linear; cropped: 192x192 of stride-201 rows).
__global__ void __launch_bounds__(256) k_gram(const bf16* __restrict__ X,
        float* __restrict__ G, float* __restrict__ S, int HR, int WR){
  __shared__ float sx[128*68];
  int b = blockIdx.y;
  int base = blockIdx.x*128;
  int npix = HR*WR;
  int tid = threadIdx.x;
  for(int idx=tid; idx<8192; idx+=256){
    int c = idx>>7, k = idx&127;
    int rp = base+k;
    float v = 0.0f;
    if(rp<npix){
      int gp;
      if(WR==NN) gp = rp;
      else { int hh=rp/WR, ww=rp-hh*WR; gp = hh*NN+ww; }
      v = b2f(X[((size_t)b*64+c)*NPIX + gp]);
    }
    sx[k*68+c] = v;
  }
  __syncthreads();
  int wid = tid>>6, lane = tid&63;
  int i0 = (lane>>3)*8, j0 = (lane&7)*8;
  float acc[8][8];
  #pragma unroll
  for(int r=0;r<8;r++){
    #pragma unroll
    for(int s=0;s<8;s++) acc[r][s]=0.f;
  }
  for(int pp=0;pp<32;pp++){
    const float* row = sx + (wid*32+pp)*68;
    const float4* ri = (const float4*)(row + i0);
    const float4* rj = (const float4*)(row + j0);
    float4 xi0 = ri[0], xi1 = ri[1];
    float4 xj0 = rj[0], xj1 = rj[1];
    float xi[8] = {xi0.x,xi0.y,xi0.z,xi0.w, xi1.x,xi1.y,xi1.z,xi1.w};
    float xj[8] = {xj0.x,xj0.y,xj0.z,xj0.w, xj1.x,xj1.y,xj1.z,xj1.w};
    #pragma unroll
    for(int r=0;r<8;r++){
      #pragma unroll
      for(int s=0;s<8;s++) acc[r][s] += xi[r]*xj[s];
    }
  }
  float* Gb = G + (size_t)b*4096;
  #pragma unroll
  for(int r=0;r<8;r++){
    #pragma unroll
    for(int s=0;s<8;s++) atomicAdd(&Gb[(i0+r)*64 + (j0+s)], acc[r][s]);
  }
  if(tid<64){
    float s2=0.f;
    for(int k=0;k<128;k++) s2 += sx[k*68+tid];
    atomicAdd(&S[b*64+tid], s2);
  }
}

// GN stats for conv output (Cout=64, groups of 32) from Gram: blocks=B, 256 thr.
__global__ void k_stats64(const float* __restrict__ W, const float* __restrict__ bias,
                          const float* __restrict__ G, const float* __restrict__ S,
                          float* __restrict__ stat, float Nf){
  __shared__ float rs[256], rq[256];
  int b=blockIdx.x, t=threadIdx.x;
  int o = t&63, sl = t>>6;
  float w[64];
  #pragma unroll
  for(int j2=0;j2<64;j2++) w[j2]=W[(size_t)o*64+j2];
  float wl[16];
  #pragma unroll
  for(int r=0;r<16;r++) wl[r]=W[(size_t)o*64 + sl*16 + r];
  const float* Gr = G + (size_t)b*4096 + (size_t)(sl*16)*64;
  float quad=0.f;
  #pragma unroll
  for(int r=0;r<16;r++){
    const float* gr = Gr + r*64;
    float tt=0.f;
    #pragma unroll
    for(int j2=0;j2<64;j2++) tt += gr[j2]*w[j2];
    quad += wl[r]*tt;
  }
  float dot=0.f;
  #pragma unroll
  for(int j2=0;j2<64;j2++) dot += w[j2]*S[b*64+j2];
  float bo = bias[o];
  float sm = (sl==0)? (dot + Nf*bo) : 0.f;
  float sq = quad + ((sl==0)? (2.f*bo*dot + Nf*bo*bo) : 0.f);
  rs[t]=sm; rq[t]=sq;
  __syncthreads();
  if(t<64){
    float s2 = rs[t]+rs[t+64]+rs[t+128]+rs[t+192];
    float q2 = rq[t]+rq[t+64]+rq[t+128]+rq[t+192];
    for(int off=16;off>0;off>>=1){
      s2 += __shfl_down(s2,off,32);
      q2 += __shfl_down(q2,off,32);
    }
    if((t&31)==0){
      int g=t>>5;
      float invN = 1.f/(Nf*32.f);
      float mean = s2*invN;
      float var = q2*invN - mean*mean;
      stat[b*4+g*2]   = mean;
      stat[b*4+g*2+1] = rsqrtf(fmaxf(var,0.f)+1e-5f);
    }
  }
}

// GN stats for head conv (Cout=256, groups of 128): blocks=B, 256 thr.
__global__ void k_stats256(const float* __restrict__ W, const float* __restrict__ bias,
                           const float* __restrict__ G, const float* __restrict__ S,
                           float* __restrict__ stat, float Nf){
  __shared__ float red[8];
  int b=blockIdx.x, t=threadIdx.x;
  float w[64];
  #pragma unroll
  for(int j2=0;j2<64;j2++) w[j2]=W[(size_t)t*64+j2];
  const float* Gb = G + (size_t)b*4096;
  float quad=0.f;
  #pragma unroll
  for(int i=0;i<64;i++){
    const float* gr = Gb + i*64;
    float tt=0.f;
    #pragma unroll
    for(int j2=0;j2<64;j2++) tt += gr[j2]*w[j2];
    quad += w[i]*tt;
  }
  float dot=0.f;
  #pragma unroll
  for(int j2=0;j2<64;j2++) dot += w[j2]*S[b*64+j2];
  float bo=bias[t];
  float sm = dot + Nf*bo;
  float sq = quad + 2.f*bo*dot + Nf*bo*bo;
  for(int off=32;off>0;off>>=1){
    sm += __shfl_down(sm,off,64);
    sq += __shfl_down(sq,off,64);
  }
  int wid=t>>6;
  if((t&63)==0){ red[wid*2]=sm; red[wid*2+1]=sq; }
  __syncthreads();
  if(t<2){
    float smt = red[t*4+0]+red[t*4+2];
    float sqt = red[t*4+1]+red[t*4+3];
    float invN = 1.f/(Nf*128.f);
    float mean = smt*invN;
    float var = sqt*invN - mean*mean;
    stat[b*4+t*2]   = mean;
    stat[b*4+t*2+1] = rsqrtf(fmaxf(var,0.f)+1e-5f);
  }
}

// Fused: x1 = m2w @ gelu(GN(m1w@C+m1b)) + m2b; x2 = GN(ww@A+wb); A = gelu?(x1+x2).
__global__ void __launch_bounds__(256) k_fuse(const bf16* __restrict__ C,
    bf16* __restrict__ A,
    const float* __restrict__ m1w, const float* __restrict__ m1b,
    const float* __restrict__ mg,  const float* __restrict__ mbt,
    const float* __restrict__ m2w, const float* __restrict__ m2b,
    const float* __restrict__ wwk, const float* __restrict__ wbk,
    const float* __restrict__ ng,  const float* __restrict__ nb,
    const float* __restrict__ tstat, const float* __restrict__ ustat, int last){
  int tid=threadIdx.x;
  int b=blockIdx.y;
  int p=blockIdx.x*256+tid;
  if(p>=NPIX) return;
  float tm0=tstat[b*4],tr0=tstat[b*4+1],tm1=tstat[b*4+2],tr1=tstat[b*4+3];
  float um0=ustat[b*4],ur0=ustat[b*4+1],um1=ustat[b*4+2],ur1=ustat[b*4+3];
  const bf16* cp = C + ((size_t)b*64)*NPIX + p;
  bf16* ap = A + ((size_t)b*64)*NPIX + p;
  float xin[64];
  #pragma unroll
  for(int c=0;c<64;c++) xin[c]=b2f(cp[(size_t)c*NPIX]);
  float v[64];
  #pragma unroll
  for(int o=0;o<64;o+=2){   // fully unrolled so v[] stays in registers
    float a0=m1b[o], a1=m1b[o+1];
    const float* w0=m1w+o*64;
    const float* w1=w0+64;
    #pragma unroll
    for(int i=0;i<64;i++){ a0+=w0[i]*xin[i]; a1+=w1[i]*xin[i]; }
    float mn=(o<32)?tm0:tm1, rsd=(o<32)?tr0:tr1;
    a0=(a0-mn)*rsd*mg[o]+mbt[o];
    a1=(a1-mn)*rsd*mg[o+1]+mbt[o+1];
    v[o]=gelu_f(a0); v[o+1]=gelu_f(a1);
  }
  #pragma unroll
  for(int c=0;c<64;c++) xin[c]=b2f(ap[(size_t)c*NPIX]);
  for(int o=0;o<64;o+=2){
    float x0=m2b[o], x1=m2b[o+1];
    float u0=wbk[o], u1=wbk[o+1];
    const float* w20=m2w+o*64; const float* w21=w20+64;
    const float* ww0=wwk+o*64; const float* ww1=ww0+64;
    #pragma unroll
    for(int i=0;i<64;i++){
      x0+=w20[i]*v[i]; x1+=w21[i]*v[i];
      u0+=ww0[i]*xin[i]; u1+=ww1[i]*xin[i];
    }
    float mn=(o<32)?um0:um1, rsd=(o<32)?ur0:ur1;
    u0=(u0-mn)*rsd*ng[o]+nb[o];
    u1=(u1-mn)*rsd*ng[o+1]+nb[o+1];
    float h0=x0+u0, h1=x1+u1;
    if(!last){ h0=gelu_f(h0); h1=gelu_f(h1); }
    ap[(size_t)o*NPIX]=f2b(h0);
    ap[(size_t)(o+1)*NPIX]=f2b(h1);
  }
}

// Head: out = q2w @ gelu(GN(q1w@h_crop+q1b)) + q2b, (B,192,192,1)
__global__ void __launch_bounds__(256) k_qout(const bf16* __restrict__ A,
    const float* __restrict__ q1w, const float* __restrict__ q1b,
    const float* __restrict__ qg, const float* __restrict__ qbt,
    const float* __restrict__ q2w, const float* __restrict__ q2b,
    const float* __restrict__ qstat, float* __restrict__ out){
  int tid=threadIdx.x;
  int b=blockIdx.y;
  int p=blockIdx.x*256+tid;
  int hh=p/SS, ww2=p-hh*SS;
  const bf16* apx = A + ((size_t)b*64)*NPIX + hh*NN+ww2;
  float xin[64];
  #pragma unroll
  for(int c=0;c<64;c++) xin[c]=b2f(apx[(size_t)c*NPIX]);
  float m0=qstat[b*4],r0=qstat[b*4+1],m1=qstat[b*4+2],r1=qstat[b*4+3];
  float acc=q2b[0];
  for(int o=0;o<256;o+=2){
    float a0=q1b[o], a1=q1b[o+1];
    const float* w0=q1w+(size_t)o*64;
    const float* w1=w0+64;
    #pragma unroll
    for(int i=0;i<64;i++){ a0+=w0[i]*xin[i]; a1+=w1[i]*xin[i]; }
    float mn=(o<128)?m0:m1, rsd=(o<128)?r0:r1;
    a0=(a0-mn)*rsd*qg[o]+qbt[o];
    a1=(a1-mn)*rsd*qg[o+1]+qbt[o+1];
    acc += gelu_f(a0)*q2w[o] + gelu_f(a1)*q2w[o+1];
  }
  out[(size_t)b*QPIX+p]=acc;
}

extern "C" void kernel_launch(void* const* d_in, const int* in_sizes, int n_in,
                              void* d_out, int out_size, void* d_ws, size_t ws_size,
                              hipStream_t stream){
  const float* x   = (const float*)d_in[0];
  const float* Wp  = (const float*)d_in[1];
  const float* bp  = (const float*)d_in[2];
  const float* sw1 = (const float*)d_in[3];
  const float* sw2 = (const float*)d_in[4];
  const float* m1w = (const float*)d_in[5];
  const float* m1b = (const float*)d_in[6];
  const float* mg  = (const float*)d_in[7];
  const float* mbt = (const float*)d_in[8];
  const float* m2w = (const float*)d_in[9];
  const float* m2b = (const float*)d_in[10];
  const float* ww  = (const float*)d_in[11];
  const float* wb  = (const float*)d_in[12];
  const float* ng  = (const float*)d_in[13];
  const float* nb  = (const float*)d_in[14];
  const float* q1w = (const float*)d_in[15];
  const float* q1b = (const float*)d_in[16];
  const float* qg  = (const float*)d_in[17];
  const float* qbt = (const float*)d_in[18];
  const float* q2w = (const float*)d_in[19];
  const float* q2b = (const float*)d_in[20];
  float* out = (float*)d_out;

  char* w8 = (char*)d_ws;
  const size_t ACT_B = (size_t)64*BB*NPIX*sizeof(bf16);   // 41,370,624
  bf16*  A    = (bf16*)(w8);
  bf16*  Cb   = (bf16*)(w8 + ACT_B);
  float* SPEC = (float*)(w8 + 2*ACT_B);                    // XW / Y overlay (9,879,552 B)
  float* XF   = (float*)(w8 + 2*ACT_B + 9879552);
  float* XO   = (float*)(w8 + 2*ACT_B + 9879552 + 1179648);
  float* TB   = (float*)(w8 + 2*ACT_B + 9879552 + 2*1179648);
  char*  g8   = w8 + 2*ACT_B + 9879552 + 2*1179648 + 20992; // TB=20,904B, aligned up
  float* GC   = (float*)g8;             // 8*4096
  float* SC   = GC + 32768;             // 8*64
  float* GA   = SC + 512;               // 8*4096
  float* SA   = GA + 32768;             // 8*64
  float* TSTAT= SA + 512;               // 32
  float* USTAT= TSTAT + 32;
  float* QSTAT= USTAT + 32;
  size_t needed = (size_t)(2*ACT_B) + 9879552 + 2*1179648 + 20992
                + (size_t)(32768+512)*2*4 + 3*32*4;
  if(ws_size < needed) return;   // graceful fail (signals ws too small)

  k_tab<<<11,256,0,stream>>>(TB);
  k_encoder<<<dim3(158,BB),256,0,stream>>>(x, Wp, bp, A);

  for(int l=0;l<4;l++){
    const float* sw1l = sw1 + (size_t)l*1179648;
    const float* sw2l = sw2 + (size_t)l*1179648;
    k_dftw<<<9648,256,0,stream>>>(A, TB, SPEC);
    k_dfth<<<576,256,0,stream>>>(SPEC, TB, XF);
    k_modemix<<<288,512,0,stream>>>(XF, sw1l, sw2l, XO);
    k_idfth<<<4824,256,0,stream>>>(XO, TB, SPEC);
    k_idftw<<<80802,256,0,stream>>>(SPEC, TB, Cb);
    hipMemsetAsync(GC, 0, (size_t)(32768+512)*2*4, stream);
    k_gram<<<dim3(316,BB),256,0,stream>>>(Cb, GC, SC, NN, NN);
    k_gram<<<dim3(316,BB),256,0,stream>>>(A,  GA, SA, NN, NN);
    k_stats64<<<BB,256,0,stream>>>(m1w + (size_t)l*4096, m1b + l*64, GC, SC, TSTAT, (float)NPIX);
    k_stats64<<<BB,256,0,stream>>>(ww  + (size_t)l*4096, wb  + l*64, GA, SA, USTAT, (float)NPIX);
    k_fuse<<<dim3(158,BB),256,0,stream>>>(Cb, A,
          m1w + (size_t)l*4096, m1b + l*64, mg + l*64, mbt + l*64,
          m2w + (size_t)l*4096, m2b + l*64,
          ww  + (size_t)l*4096, wb  + l*64, ng + l*64, nb + l*64,
          TSTAT, USTAT, (l==3)?1:0);
  }

  hipMemsetAsync(GC, 0, (size_t)(32768+512)*4, stream);
  k_gram<<<dim3(288,BB),256,0,stream>>>(A, GC, SC, SS, SS);
  k_stats256<<<BB,256,0,stream>>>(q1w, q1b, GC, SC, QSTAT, (float)QPIX);
  k_qout<<<dim3(144,BB),256,0,stream>>>(A, q1w, q1b, qg, qbt, q2w, q2b, QSTAT, out);
}

// Round 4
// 4455.848 us; speedup vs baseline: 4.1067x; 4.1067x over previous
//
#include <hip/hip_runtime.h>
#include <hip/hip_bf16.h>
#include <math.h>

// FNO2d: B=8, S=192, pad->201x201, C=64, modes 12x12 (ky in {0..11,189..200}), 4 layers.
// Partial-DFT formulation + Gram-matrix GroupNorm stats (no bypass/head buffers).
// Activations bf16. Gram = register-tile partials + tree reduce (NO atomics).

#define NN 201
#define SS 192
#define NPIX 40401      // 201*201
#define QPIX 36864      // 192*192
#define BB 8
#define RR_TOT 102912   // 512*201 rows (bc*201+h)
#define GNB 40          // max gram partial blocks per (z,b)
#define PI_F 3.14159265358979323846f

typedef __hip_bfloat16 bf16;

__device__ __forceinline__ float gelu_f(float x){
  return 0.5f*x*(1.0f+erff(x*0.7071067811865476f));
}
__device__ __forceinline__ float b2f(bf16 v){ return __bfloat162float(v); }
__device__ __forceinline__ bf16  f2b(float v){ return __float2bfloat16(v); }

// tab[k][n][0]=cos(2*pi*k*n/201), [1]=sin, k=0..12, n=0..200 (k*n reduced mod 201 exactly)
__global__ void k_tab(float* __restrict__ tab){
  int t = blockIdx.x*blockDim.x+threadIdx.x;
  if(t>=13*NN) return;
  int k=t/NN, n=t-k*NN;
  int m=(k*n)%NN;
  float ang = (2.0f*PI_F/201.0f)*(float)m;
  tab[2*t]   = cosf(ang);
  tab[2*t+1] = sinf(ang);
}

// h0[b][c][p] = (feat(43) @ Wp)[c] + bp[c]; zero in pad region. bf16 out.
__global__ void k_encoder(const float* __restrict__ x, const float* __restrict__ Wp,
                          const float* __restrict__ bp, bf16* __restrict__ A){
  int tid=threadIdx.x;
  int p = blockIdx.x*256+tid;
  if(p>=NPIX) return;
  int b = blockIdx.y;
  bf16* out = A + ((size_t)b*64)*NPIX + p;
  int hh=p/NN, ww=p-hh*NN;
  if(hh>=SS || ww>=SS){
    for(int o=0;o<64;o++) out[(size_t)o*NPIX]=f2b(0.0f);
    return;
  }
  float feat[43];
  float gx = (float)hh*(1.0f/191.0f);
  float gy = (float)ww*(1.0f/191.0f);
  feat[0]=x[((size_t)b*SS+hh)*SS+ww];
  feat[1]=gx; feat[2]=gy;
  #pragma unroll
  for(int l=0;l<10;l++){
    float f = PI_F*(float)(1<<l);
    float sxv,cxv,syv,cyv;
    sincosf(gx*f,&sxv,&cxv);
    sincosf(gy*f,&syv,&cyv);
    feat[3+2*l]=cxv;  feat[4+2*l]=cyv;
    feat[23+2*l]=sxv; feat[24+2*l]=syv;
  }
  for(int o=0;o<64;o+=2){
    float a0=bp[o], a1=bp[o+1];
    #pragma unroll
    for(int j=0;j<43;j++){ a0 += feat[j]*Wp[j*64+o]; a1 += feat[j]*Wp[j*64+o+1]; }
    out[(size_t)o*NPIX]=f2b(a0);
    out[(size_t)(o+1)*NPIX]=f2b(a1);
  }
}

// Forward DFT along W. One thread per row rr=bc*201+h, 12 complex accs in regs.
// Output transposed: XW[q][rr], q=kx*2+comp; im carries the e^{-i} minus sign.
__global__ void __launch_bounds__(256) k_dftw(const bf16* __restrict__ A,
        const float* __restrict__ tab, float* __restrict__ XW){
  __shared__ float st[12*NN*2];
  int tid=threadIdx.x;
  for(int i=tid;i<12*NN*2;i+=256) st[i]=tab[i];
  __syncthreads();
  int rr=blockIdx.x*256+tid;      // grid 402 -> exactly RR_TOT
  const bf16* row = A + (size_t)rr*NN;   // rr*201 == bc*NPIX + h*201
  float ar[12], ai[12];
  #pragma unroll
  for(int k=0;k<12;k++){ ar[k]=0.f; ai[k]=0.f; }
  for(int w=0;w<NN;w++){
    float a=b2f(row[w]);
    const float* tw = st + 2*w;
    #pragma unroll
    for(int k=0;k<12;k++){
      ar[k] += a*tw[k*NN*2];
      ai[k] += a*tw[k*NN*2+1];
    }
  }
  #pragma unroll
  for(int k=0;k<12;k++){
    XW[(size_t)(2*k)*RR_TOT + rr]   = ar[k];
    XW[(size_t)(2*k+1)*RR_TOT + rr] = -ai[k];
  }
}

// Forward DFT along H: XF[m][bc][{re,im}], m=j*12+kx; j<12 -> ky=j (e^{-i}), j>=12 -> ky=177+j == e^{+i w (24-j) h}
// Reads XW[q][bc*201+h]: thread-contiguous streams.
__global__ void k_dfth(const float* __restrict__ XW, const float* __restrict__ tab,
                       float* __restrict__ XF){
  __shared__ float st[NN*2];
  int m = blockIdx.x>>1;          // 576 blocks
  int half = blockIdx.x&1;
  int j=m/12, kx=m-j*12;
  int k2 = (j<12)? j : 24-j;
  float sgn = (j<12)? -1.0f : 1.0f;
  int tid=threadIdx.x;
  for(int i=tid;i<NN*2;i+=256) st[i]=tab[k2*NN*2+i];
  __syncthreads();
  int bc = half*256+tid;
  const float* re = XW + (size_t)(kx*2)*RR_TOT + (size_t)bc*NN;
  const float* im = re + RR_TOT;
  float sre=0.f,sim=0.f;
  for(int h2=0;h2<NN;h2++){
    float a=re[h2], b2=im[h2];
    float c=st[2*h2], s2=sgn*st[2*h2+1];
    sre += a*c - b2*s2;
    sim += a*s2 + b2*c;
  }
  XF[(size_t)m*1024 + bc*2]   = sre;
  XF[(size_t)m*1024 + bc*2+1] = sim;
}

// Per-mode 64x64 complex mix
__global__ void __launch_bounds__(512) k_modemix(const float* __restrict__ XF,
     const float* __restrict__ w1, const float* __restrict__ w2,
     float* __restrict__ XO){
  __shared__ float sx[1024];
  __shared__ float swr[4096], swi[4096];
  int m=blockIdx.x;
  int j=m/12, kx=m-j*12;
  int tid=threadIdx.x;
  sx[tid]     = XF[(size_t)m*1024+tid];
  sx[tid+512] = XF[(size_t)m*1024+tid+512];
  const float* wsrc = (j<12)? w1 : w2;
  int xi = (j<12)? j : j-12;
  size_t base=((size_t)xi*12+kx)*2;
  for(int io=tid;io<4096;io+=512){
    swr[io]=wsrc[(size_t)io*288+base];
    swi[io]=wsrc[(size_t)io*288+base+1];
  }
  __syncthreads();
  int b=tid>>6, o=tid&63;
  const float* xb = sx + b*128;
  float re=0.0f,im=0.0f;
  #pragma unroll 8
  for(int i=0;i<64;i++){
    float a=xb[2*i], b2=xb[2*i+1];
    float c=swr[i*64+o], d=swi[i*64+o];
    re += a*c - b2*d;
    im += a*d + b2*c;
  }
  XO[2*((size_t)m*512+tid)]  =re;
  XO[2*((size_t)m*512+tid)+1]=im;
}

// Inverse DFT along H: Y[bo][h][kx] = sum_j XO[j*12+kx][b][o] * e^{+i w ky_j h}
__global__ void k_idfth(const float* __restrict__ XO, const float* __restrict__ tab,
                        float* __restrict__ Y){
  int t=blockIdx.x*256+threadIdx.x;
  if(t>=512*NN*12) return;
  int kx=t%12;
  int rem=t/12;
  int h2=rem%NN;
  int bo=rem/NN;
  int b=bo>>6, o=bo&63;
  float re=0.0f,im=0.0f;
  #pragma unroll
  for(int j=0;j<24;j++){
    int k2=(j<12)?j:24-j;
    float sgn=(j<12)?1.0f:-1.0f;
    const float* xo = XO + 2*(((size_t)(j*12+kx)*8+b)*64+o);
    float a=xo[0], b2=xo[1];
    const float* tb=tab+ (k2*NN+h2)*2;
    float c=tb[0], s2=sgn*tb[1];
    re += a*c - b2*s2;
    im += a*s2 + b2*c;
  }
  Y[2*t]=re; Y[2*t+1]=im;
}

// Inverse C2R along W + 1/N^2. bf16 out. y rows via aligned float4.
__global__ void k_idftw(const float* __restrict__ Y, const float* __restrict__ tab,
                        bf16* __restrict__ C){
  __shared__ float st[12*NN*2];
  int tid=threadIdx.x;
  for(int i=tid;i<12*NN*2;i+=256) st[i]=tab[i];
  __syncthreads();
  int t=blockIdx.x*256+tid;
  int p=t%NPIX;
  int bo=t/NPIX;
  int h2=p/NN, w2=p-h2*NN;
  const float4* y4 = (const float4*)(Y + ((size_t)bo*NN+h2)*24);
  float4 q0=y4[0],q1=y4[1],q2=y4[2],q3=y4[3],q4=y4[4],q5=y4[5];
  float yv[24]={q0.x,q0.y,q0.z,q0.w, q1.x,q1.y,q1.z,q1.w,
                q2.x,q2.y,q2.z,q2.w, q3.x,q3.y,q3.z,q3.w,
                q4.x,q4.y,q4.z,q4.w, q5.x,q5.y,q5.z,q5.w};
  float acc=yv[0];
  #pragma unroll
  for(int k=1;k<12;k++){
    acc += 2.0f*( yv[2*k]*st[(k*NN+w2)*2] - yv[2*k+1]*st[(k*NN+w2)*2+1] );
  }
  C[t]=f2b(acc*(1.0f/40401.0f));
}

// Gram partials, NO atomics. grid (nblk, BB, nsrc); block owns pixels [blk*1024, blk*1024+1024).
// Writes Gpart[zb*GNB+blk][4096] and Spart[zb*GNB+blk][64].
__global__ void __launch_bounds__(256) k_gramp(const bf16* __restrict__ s0,
        const bf16* __restrict__ s1, float* __restrict__ Gpart,
        float* __restrict__ Spart, int HR, int WR){
  __shared__ float sx[8704];      // 128*68 staging; reduction reuses [0,8320)+scol[8320,8576)
  int b = blockIdx.y, blk = blockIdx.x, z = blockIdx.z;
  const bf16* X = (z==0)? s0 : s1;
  int zb = z*BB + b;
  int npix = HR*WR;
  int tid = threadIdx.x;
  int wid = tid>>6, lane = tid&63;
  int i0 = (lane>>3)*8, j0 = (lane&7)*8;
  float acc[8][8];
  #pragma unroll
  for(int r=0;r<8;r++){
    #pragma unroll
    for(int s=0;s<8;s++) acc[r][s]=0.f;
  }
  float cs = 0.f;
  for(int tile=0;tile<8;tile++){
    int rp0 = blk*1024 + tile*128;
    __syncthreads();
    for(int idx=tid; idx<8192; idx+=256){
      int c = idx>>7, k = idx&127;
      int rp = rp0+k;
      float v = 0.0f;
      if(rp<npix){
        int gp;
        if(WR==NN) gp = rp;
        else { int hh=rp/WR, ww=rp-hh*WR; gp = hh*NN+ww; }
        v = b2f(X[((size_t)b*64+c)*NPIX + gp]);
      }
      sx[k*68+c] = v;
    }
    __syncthreads();
    for(int pp=0;pp<32;pp++){
      const float* row = sx + (wid*32+pp)*68;
      cs += row[lane];
      const float4* ri = (const float4*)(row + i0);
      const float4* rj = (const float4*)(row + j0);
      float4 xi0 = ri[0], xi1 = ri[1];
      float4 xj0 = rj[0], xj1 = rj[1];
      float xi[8] = {xi0.x,xi0.y,xi0.z,xi0.w, xi1.x,xi1.y,xi1.z,xi1.w};
      float xj[8] = {xj0.x,xj0.y,xj0.z,xj0.w, xj1.x,xj1.y,xj1.z,xj1.w};
      #pragma unroll
      for(int r=0;r<8;r++){
        #pragma unroll
        for(int s=0;s<8;s++) acc[r][s] += xi[r]*xj[s];
      }
    }
  }
  // cross-wave reduce (65-stride: bank-conflict-free)
  __syncthreads();
  float* scol = sx + 8320;
  scol[tid] = cs;
  if(wid>=2){
    float* d = sx + (tid-128)*65;
    #pragma unroll
    for(int r=0;r<8;r++){
      #pragma unroll
      for(int s=0;s<8;s++) d[r*8+s]=acc[r][s];
    }
  }
  __syncthreads();
  if(wid<2){
    const float* d = sx + tid*65;
    #pragma unroll
    for(int r=0;r<8;r++){
      #pragma unroll
      for(int s=0;s<8;s++) acc[r][s]+=d[r*8+s];
    }
  }
  if(tid<64){
    float tot = scol[tid]+scol[tid+64]+scol[tid+128]+scol[tid+192];
    Spart[((size_t)zb*GNB + blk)*64 + tid] = tot;
  }
  __syncthreads();
  if(wid==1){
    float* d = sx + (tid-64)*65;
    #pragma unroll
    for(int r=0;r<8;r++){
      #pragma unroll
      for(int s=0;s<8;s++) d[r*8+s]=acc[r][s];
    }
  }
  __syncthreads();
  if(wid==0){
    const float* d = sx + tid*65;
    #pragma unroll
    for(int r=0;r<8;r++){
      #pragma unroll
      for(int s=0;s<8;s++) acc[r][s]+=d[r*8+s];
    }
    float* g = Gpart + ((size_t)zb*GNB + blk)*4096;
    #pragma unroll
    for(int r=0;r<8;r++){
      #pragma unroll
      for(int s=0;s<8;s++) g[(i0+r)*64 + (j0+s)] = acc[r][s];
    }
  }
}

// Reduce partial slabs -> G[zb][4096], S[zb][64]. grid = nzb blocks.
__global__ void k_gramr(const float* __restrict__ Gpart, const float* __restrict__ Spart,
                        float* __restrict__ G, float* __restrict__ S, int nblk){
  int zb = blockIdx.x; int tid = threadIdx.x;
  float a[16];
  #pragma unroll
  for(int e=0;e<16;e++) a[e]=0.f;
  for(int k=0;k<nblk;k++){
    const float* g = Gpart + ((size_t)zb*GNB + k)*4096 + tid*16;
    #pragma unroll
    for(int e=0;e<16;e++) a[e]+=g[e];
  }
  float* go = G + (size_t)zb*4096 + tid*16;
  #pragma unroll
  for(int e=0;e<16;e++) go[e]=a[e];
  if(tid<64){
    float s=0.f;
    for(int k=0;k<nblk;k++) s += Spart[((size_t)zb*GNB + k)*64 + tid];
    S[(size_t)zb*64 + tid]=s;
  }
}

// GN stats for conv output (Cout=64, groups of 32) from Gram: blocks=B, 256 thr.
__global__ void k_stats64(const float* __restrict__ W, const float* __restrict__ bias,
                          const float* __restrict__ G, const float* __restrict__ S,
                          float* __restrict__ stat, float Nf){
  __shared__ float rs[256], rq[256];
  int b=blockIdx.x, t=threadIdx.x;
  int o = t&63, sl = t>>6;
  float w[64];
  #pragma unroll
  for(int j2=0;j2<64;j2++) w[j2]=W[(size_t)o*64+j2];
  float wl[16];
  #pragma unroll
  for(int r=0;r<16;r++) wl[r]=W[(size_t)o*64 + sl*16 + r];
  const float* Gr = G + (size_t)b*4096 + (size_t)(sl*16)*64;
  float quad=0.f;
  #pragma unroll
  for(int r=0;r<16;r++){
    const float* gr = Gr + r*64;
    float tt=0.f;
    #pragma unroll
    for(int j2=0;j2<64;j2++) tt += gr[j2]*w[j2];
    quad += wl[r]*tt;
  }
  float dot=0.f;
  #pragma unroll
  for(int j2=0;j2<64;j2++) dot += w[j2]*S[b*64+j2];
  float bo = bias[o];
  float sm = (sl==0)? (dot + Nf*bo) : 0.f;
  float sq = quad + ((sl==0)? (2.f*bo*dot + Nf*bo*bo) : 0.f);
  rs[t]=sm; rq[t]=sq;
  __syncthreads();
  if(t<64){
    float s2 = rs[t]+rs[t+64]+rs[t+128]+rs[t+192];
    float q2 = rq[t]+rq[t+64]+rq[t+128]+rq[t+192];
    for(int off=16;off>0;off>>=1){
      s2 += __shfl_down(s2,off,32);
      q2 += __shfl_down(q2,off,32);
    }
    if((t&31)==0){
      int g=t>>5;
      float invN = 1.f/(Nf*32.f);
      float mean = s2*invN;
      float var = q2*invN - mean*mean;
      stat[b*4+g*2]   = mean;
      stat[b*4+g*2+1] = rsqrtf(fmaxf(var,0.f)+1e-5f);
    }
  }
}

// GN stats for head conv (Cout=256, groups of 128): blocks=B, 256 thr.
__global__ void k_stats256(const float* __restrict__ W, const float* __restrict__ bias,
                           const float* __restrict__ G, const float* __restrict__ S,
                           float* __restrict__ stat, float Nf){
  __shared__ float red[8];
  int b=blockIdx.x, t=threadIdx.x;
  float w[64];
  #pragma unroll
  for(int j2=0;j2<64;j2++) w[j2]=W[(size_t)t*64+j2];
  const float* Gb = G + (size_t)b*4096;
  float quad=0.f;
  #pragma unroll
  for(int i=0;i<64;i++){
    const float* gr = Gb + i*64;
    float tt=0.f;
    #pragma unroll
    for(int j2=0;j2<64;j2++) tt += gr[j2]*w[j2];
    quad += w[i]*tt;
  }
  float dot=0.f;
  #pragma unroll
  for(int j2=0;j2<64;j2++) dot += w[j2]*S[b*64+j2];
  float bo=bias[t];
  float sm = dot + Nf*bo;
  float sq = quad + 2.f*bo*dot + Nf*bo*bo;
  for(int off=32;off>0;off>>=1){
    sm += __shfl_down(sm,off,64);
    sq += __shfl_down(sq,off,64);
  }
  int wid=t>>6;
  if((t&63)==0){ red[wid*2]=sm; red[wid*2+1]=sq; }
  __syncthreads();
  if(t<2){
    float smt = red[t*4+0]+red[t*4+2];
    float sqt = red[t*4+1]+red[t*4+3];
    float invN = 1.f/(Nf*128.f);
    float mean = smt*invN;
    float var = sqt*invN - mean*mean;
    stat[b*4+t*2]   = mean;
    stat[b*4+t*2+1] = rsqrtf(fmaxf(var,0.f)+1e-5f);
  }
}

// Fused: x1 = m2w @ gelu(GN(m1w@C+m1b)) + m2b; x2 = GN(ww@A+wb); A = gelu?(x1+x2).
__global__ void __launch_bounds__(256) k_fuse(const bf16* __restrict__ C,
    bf16* __restrict__ A,
    const float* __restrict__ m1w, const float* __restrict__ m1b,
    const float* __restrict__ mg,  const float* __restrict__ mbt,
    const float* __restrict__ m2w, const float* __restrict__ m2b,
    const float* __restrict__ wwk, const float* __restrict__ wbk,
    const float* __restrict__ ng,  const float* __restrict__ nb,
    const float* __restrict__ tstat, const float* __restrict__ ustat, int last){
  int tid=threadIdx.x;
  int b=blockIdx.y;
  int p=blockIdx.x*256+tid;
  if(p>=NPIX) return;
  float tm0=tstat[b*4],tr0=tstat[b*4+1],tm1=tstat[b*4+2],tr1=tstat[b*4+3];
  float um0=ustat[b*4],ur0=ustat[b*4+1],um1=ustat[b*4+2],ur1=ustat[b*4+3];
  const bf16* cp = C + ((size_t)b*64)*NPIX + p;
  bf16* ap = A + ((size_t)b*64)*NPIX + p;
  float xin[64];
  #pragma unroll
  for(int c=0;c<64;c++) xin[c]=b2f(cp[(size_t)c*NPIX]);
  float v[64];
  #pragma unroll
  for(int o=0;o<64;o+=2){
    float a0=m1b[o], a1=m1b[o+1];
    const float* w0=m1w+o*64;
    const float* w1=w0+64;
    #pragma unroll
    for(int i=0;i<64;i++){ a0+=w0[i]*xin[i]; a1+=w1[i]*xin[i]; }
    float mn=(o<32)?tm0:tm1, rsd=(o<32)?tr0:tr1;
    a0=(a0-mn)*rsd*mg[o]+mbt[o];
    a1=(a1-mn)*rsd*mg[o+1]+mbt[o+1];
    v[o]=gelu_f(a0); v[o+1]=gelu_f(a1);
  }
  #pragma unroll
  for(int c=0;c<64;c++) xin[c]=b2f(ap[(size_t)c*NPIX]);
  for(int o=0;o<64;o+=2){
    float x0=m2b[o], x1=m2b[o+1];
    float u0=wbk[o], u1=wbk[o+1];
    const float* w20=m2w+o*64; const float* w21=w20+64;
    const float* ww0=wwk+o*64; const float* ww1=ww0+64;
    #pragma unroll
    for(int i=0;i<64;i++){
      x0+=w20[i]*v[i]; x1+=w21[i]*v[i];
      u0+=ww0[i]*xin[i]; u1+=ww1[i]*xin[i];
    }
    float mn=(o<32)?um0:um1, rsd=(o<32)?ur0:ur1;
    u0=(u0-mn)*rsd*ng[o]+nb[o];
    u1=(u1-mn)*rsd*ng[o+1]+nb[o+1];
    float h0=x0+u0, h1=x1+u1;
    if(!last){ h0=gelu_f(h0); h1=gelu_f(h1); }
    ap[(size_t)o*NPIX]=f2b(h0);
    ap[(size_t)(o+1)*NPIX]=f2b(h1);
  }
}

// Head: out = q2w @ gelu(GN(q1w@h_crop+q1b)) + q2b, (B,192,192,1)
__global__ void __launch_bounds__(256) k_qout(const bf16* __restrict__ A,
    const float* __restrict__ q1w, const float* __restrict__ q1b,
    const float* __restrict__ qg, const float* __restrict__ qbt,
    const float* __restrict__ q2w, const float* __restrict__ q2b,
    const float* __restrict__ qstat, float* __restrict__ out){
  int tid=threadIdx.x;
  int b=blockIdx.y;
  int p=blockIdx.x*256+tid;
  int hh=p/SS, ww2=p-hh*SS;
  const bf16* apx = A + ((size_t)b*64)*NPIX + hh*NN+ww2;
  float xin[64];
  #pragma unroll
  for(int c=0;c<64;c++) xin[c]=b2f(apx[(size_t)c*NPIX]);
  float m0=qstat[b*4],r0=qstat[b*4+1],m1=qstat[b*4+2],r1=qstat[b*4+3];
  float acc=q2b[0];
  for(int o=0;o<256;o+=2){
    float a0=q1b[o], a1=q1b[o+1];
    const float* w0=q1w+(size_t)o*64;
    const float* w1=w0+64;
    #pragma unroll
    for(int i=0;i<64;i++){ a0+=w0[i]*xin[i]; a1+=w1[i]*xin[i]; }
    float mn=(o<128)?m0:m1, rsd=(o<128)?r0:r1;
    a0=(a0-mn)*rsd*qg[o]+qbt[o];
    a1=(a1-mn)*rsd*qg[o+1]+qbt[o+1];
    acc += gelu_f(a0)*q2w[o] + gelu_f(a1)*q2w[o+1];
  }
  out[(size_t)b*QPIX+p]=acc;
}

extern "C" void kernel_launch(void* const* d_in, const int* in_sizes, int n_in,
                              void* d_out, int out_size, void* d_ws, size_t ws_size,
                              hipStream_t stream){
  const float* x   = (const float*)d_in[0];
  const float* Wp  = (const float*)d_in[1];
  const float* bp  = (const float*)d_in[2];
  const float* sw1 = (const float*)d_in[3];
  const float* sw2 = (const float*)d_in[4];
  const float* m1w = (const float*)d_in[5];
  const float* m1b = (const float*)d_in[6];
  const float* mg  = (const float*)d_in[7];
  const float* mbt = (const float*)d_in[8];
  const float* m2w = (const float*)d_in[9];
  const float* m2b = (const float*)d_in[10];
  const float* ww  = (const float*)d_in[11];
  const float* wb  = (const float*)d_in[12];
  const float* ng  = (const float*)d_in[13];
  const float* nb  = (const float*)d_in[14];
  const float* q1w = (const float*)d_in[15];
  const float* q1b = (const float*)d_in[16];
  const float* qg  = (const float*)d_in[17];
  const float* qbt = (const float*)d_in[18];
  const float* q2w = (const float*)d_in[19];
  const float* q2b = (const float*)d_in[20];
  float* out = (float*)d_out;

  char* w8 = (char*)d_ws;
  const size_t ACT_B = (size_t)64*BB*NPIX*sizeof(bf16);   // 41,370,624
  bf16*  A    = (bf16*)(w8);
  bf16*  Cb   = (bf16*)(w8 + ACT_B);
  float* SPEC = (float*)(w8 + 2*ACT_B);                    // XW / Y / Gram-partial overlay
  float* XF   = (float*)(w8 + 2*ACT_B + 9879552);
  float* XO   = (float*)(w8 + 2*ACT_B + 9879552 + 1179648);
  float* TB   = (float*)(w8 + 2*ACT_B + 9879552 + 2*1179648);
  char*  g8   = w8 + 2*ACT_B + 9879552 + 2*1179648 + 20992;
  float* Gfin = (float*)g8;             // 16*4096 floats
  float* Sfin = Gfin + 16*4096;         // 16*64
  float* TSTAT= (float*)(g8 + (size_t)(32768+512)*2*4);
  float* USTAT= TSTAT + 32;
  float* QSTAT= USTAT + 32;
  // Gram partials overlay dead spectral scratch (SPEC+XF): 10.65 MB <= 11.06 MB
  float* Gpart = SPEC;                               // 16*GNB*4096 floats
  float* Spart = Gpart + (size_t)16*GNB*4096;        // 16*GNB*64 floats
  size_t needed = (size_t)(2*ACT_B) + 9879552 + 2*1179648 + 20992
                + (size_t)(32768+512)*2*4 + 3*32*4;
  if(ws_size < needed) return;   // graceful fail (signals ws too small)

  k_tab<<<11,256,0,stream>>>(TB);
  k_encoder<<<dim3(158,BB),256,0,stream>>>(x, Wp, bp, A);

  for(int l=0;l<4;l++){
    const float* sw1l = sw1 + (size_t)l*1179648;
    const float* sw2l = sw2 + (size_t)l*1179648;
    k_dftw<<<402,256,0,stream>>>(A, TB, SPEC);
    k_dfth<<<576,256,0,stream>>>(SPEC, TB, XF);
    k_modemix<<<288,512,0,stream>>>(XF, sw1l, sw2l, XO);
    k_idfth<<<4824,256,0,stream>>>(XO, TB, SPEC);
    k_idftw<<<80802,256,0,stream>>>(SPEC, TB, Cb);
    k_gramp<<<dim3(GNB,BB,2),256,0,stream>>>(Cb, A, Gpart, Spart, NN, NN);
    k_gramr<<<16,256,0,stream>>>(Gpart, Spart, Gfin, Sfin, GNB);
    k_stats64<<<BB,256,0,stream>>>(m1w + (size_t)l*4096, m1b + l*64, Gfin, Sfin, TSTAT, (float)NPIX);
    k_stats64<<<BB,256,0,stream>>>(ww  + (size_t)l*4096, wb  + l*64, Gfin + (size_t)8*4096, Sfin + 8*64, USTAT, (float)NPIX);
    k_fuse<<<dim3(158,BB),256,0,stream>>>(Cb, A,
          m1w + (size_t)l*4096, m1b + l*64, mg + l*64, mbt + l*64,
          m2w + (size_t)l*4096, m2b + l*64,
          ww  + (size_t)l*4096, wb  + l*64, ng + l*64, nb + l*64,
          TSTAT, USTAT, (l==3)?1:0);
  }

  k_gramp<<<dim3(36,BB,1),256,0,stream>>>(A, A, Gpart, Spart, SS, SS);
  k_gramr<<<BB,256,0,stream>>>(Gpart, Spart, Gfin, Sfin, 36);
  k_stats256<<<BB,256,0,stream>>>(q1w, q1b, Gfin, Sfin, QSTAT, (float)QPIX);
  k_qout<<<dim3(144,BB),256,0,stream>>>(A, q1w, q1b, qg, qbt, q2w, q2b, QSTAT, out);
}

// Round 5
// 2604.747 us; speedup vs baseline: 7.0252x; 1.7107x over previous
//
#include <hip/hip_runtime.h>
#include <hip/hip_bf16.h>
#include <math.h>

// FNO2d: B=8, S=192, pad->201x201, C=64, modes 12x12, 4 layers.
// Pixel-major activations [b][p][c] (c contiguous) + MFMA conv GEMMs.
// Partial-DFT spectral path; Gram-matrix GroupNorm stats (bf16-rounded weights).

#define NN 201
#define SS 192
#define NPIX 40401
#define QPIX 36864
#define BB 8
#define GNB 40
#define XWPL 1234944     // 1608*12*64 (re/im plane stride in floats)
#define PI_F 3.14159265358979323846f

typedef __hip_bfloat16 bf16;
typedef __attribute__((ext_vector_type(8))) short s8v;
typedef __attribute__((ext_vector_type(4))) float f32x4;

__device__ __forceinline__ float gelu_f(float x){
  return 0.5f*x*(1.0f+erff(x*0.7071067811865476f));
}
__device__ __forceinline__ float b2f(bf16 v){ return __bfloat162float(v); }
__device__ __forceinline__ bf16  f2b(float v){ return __float2bfloat16(v); }
__device__ __forceinline__ unsigned short f2bu(float x){
  bf16 h = __float2bfloat16(x);
  unsigned short u; __builtin_memcpy(&u,&h,2); return u;
}
__device__ __forceinline__ float bu2f(unsigned short u){
  unsigned int x = ((unsigned int)u)<<16; float f; __builtin_memcpy(&f,&x,4); return f;
}

// tab[k][n]: cos/sin(2*pi*k*n/201), k=0..12, exact mod-201 reduction
__global__ void k_tab(float* __restrict__ tab){
  int t = blockIdx.x*blockDim.x+threadIdx.x;
  if(t>=13*NN) return;
  int k=t/NN, n=t-k*NN;
  int m=(k*n)%NN;
  float ang = (2.0f*PI_F/201.0f)*(float)m;
  tab[2*t]   = cosf(ang);
  tab[2*t+1] = sinf(ang);
}

// encoder: A[b][p][c] = feat(43)@Wp + bp; zeros in pad. bf16, c-contiguous.
__global__ void k_encoder(const float* __restrict__ x, const float* __restrict__ Wp,
                          const float* __restrict__ bp, bf16* __restrict__ A){
  int tid=threadIdx.x;
  int p = blockIdx.x*256+tid;
  if(p>=NPIX) return;
  int b = blockIdx.y;
  uint4* dst = (uint4*)(A + ((size_t)b*NPIX + p)*64);
  int hh=p/NN, ww=p-hh*NN;
  if(hh>=SS || ww>=SS){
    uint4 z = {0,0,0,0};
    #pragma unroll
    for(int i=0;i<8;i++) dst[i]=z;
    return;
  }
  float feat[43];
  float gx = (float)hh*(1.0f/191.0f);
  float gy = (float)ww*(1.0f/191.0f);
  feat[0]=x[((size_t)b*SS+hh)*SS+ww];
  feat[1]=gx; feat[2]=gy;
  #pragma unroll
  for(int l=0;l<10;l++){
    float f = PI_F*(float)(1<<l);
    float sxv,cxv,syv,cyv;
    sincosf(gx*f,&sxv,&cxv);
    sincosf(gy*f,&syv,&cyv);
    feat[3+2*l]=cxv;  feat[4+2*l]=cyv;
    feat[23+2*l]=sxv; feat[24+2*l]=syv;
  }
  float vals[64];
  #pragma unroll
  for(int o=0;o<64;o+=2){
    float a0=bp[o], a1=bp[o+1];
    #pragma unroll
    for(int j=0;j<43;j++){ a0 += feat[j]*Wp[j*64+o]; a1 += feat[j]*Wp[j*64+o+1]; }
    vals[o]=a0; vals[o+1]=a1;
  }
  #pragma unroll
  for(int i=0;i<8;i++){
    uint4 v;
    v.x = (unsigned)f2bu(vals[8*i+0]) | ((unsigned)f2bu(vals[8*i+1])<<16);
    v.y = (unsigned)f2bu(vals[8*i+2]) | ((unsigned)f2bu(vals[8*i+3])<<16);
    v.z = (unsigned)f2bu(vals[8*i+4]) | ((unsigned)f2bu(vals[8*i+5])<<16);
    v.w = (unsigned)f2bu(vals[8*i+6]) | ((unsigned)f2bu(vals[8*i+7])<<16);
    dst[i]=v;
  }
}

// DFT along W. Wave per row R=b*201+h, lane=c. XW[re/im][R][kx][c].
__global__ void __launch_bounds__(256) k_dftw(const bf16* __restrict__ A,
        const float* __restrict__ tab, float* __restrict__ XW){
  __shared__ float2 st[2412];
  int tid=threadIdx.x;
  for(int i=tid;i<2412;i+=256) st[i]=((const float2*)tab)[i];
  __syncthreads();
  int R = blockIdx.x*4 + (tid>>6);   // 402 blocks -> 1608 rows
  int l = tid&63;
  const bf16* base = A + ((size_t)R*NN)*64 + l;
  float ar0=0.f;
  float ar[11], ai[11];
  #pragma unroll
  for(int k=0;k<11;k++){ ar[k]=0.f; ai[k]=0.f; }
  for(int w=0;w<NN;w++){
    float a = b2f(base[(size_t)w*64]);
    ar0 += a;
    #pragma unroll
    for(int k=0;k<11;k++){
      float2 cs = st[(k+1)*NN+w];
      ar[k] += a*cs.x;
      ai[k] += a*cs.y;
    }
  }
  float* xre = XW + ((size_t)R*12)*64 + l;
  float* xim = xre + XWPL;
  xre[0]=ar0; xim[0]=0.f;
  #pragma unroll
  for(int k=0;k<11;k++){
    xre[(size_t)(k+1)*64] = ar[k];
    xim[(size_t)(k+1)*64] = -ai[k];
  }
}

// DFT along H: XF[m][b*64+c][{re,im}]; m=j*12+kx; j<12: e^{-i ky h}, j>=12: ky=24-j, e^{+i}
__global__ void k_dfth(const float* __restrict__ XW, const float* __restrict__ tab,
                       float* __restrict__ XF){
  __shared__ float2 st[NN];
  int bx = blockIdx.x;               // 576 = 8*24*3
  int b = bx/72, rem = bx - b*72;
  int j = rem/3, q = rem - (rem/3)*3;
  int tid=threadIdx.x;
  int kx = q*4 + (tid>>6);
  int c = tid&63;
  int k2 = (j<12)? j : 24-j;
  float sgn = (j<12)? -1.0f : 1.0f;
  for(int i=tid;i<NN;i+=256) st[i]=((const float2*)tab)[k2*NN+i];
  __syncthreads();
  const float* re = XW + (((size_t)b*NN)*12 + kx)*64 + c;
  const float* im = re + XWPL;
  float sre=0.f,sim=0.f;
  for(int h=0;h<NN;h++){
    float a = re[(size_t)h*768];
    float b2 = im[(size_t)h*768];
    float2 cs = st[h];
    float cc=cs.x, s2=sgn*cs.y;
    sre += a*cc - b2*s2;
    sim += a*s2 + b2*cc;
  }
  int m = j*12+kx;
  XF[(size_t)m*1024 + (b*64+c)*2]   = sre;
  XF[(size_t)m*1024 + (b*64+c)*2+1] = sim;
}

// per-mode 64x64 complex mix (unchanged)
__global__ void __launch_bounds__(512) k_modemix(const float* __restrict__ XF,
     const float* __restrict__ w1, const float* __restrict__ w2,
     float* __restrict__ XO){
  __shared__ float sx[1024];
  __shared__ float swr[4096], swi[4096];
  int m=blockIdx.x;
  int j=m/12, kx=m-j*12;
  int tid=threadIdx.x;
  sx[tid]     = XF[(size_t)m*1024+tid];
  sx[tid+512] = XF[(size_t)m*1024+tid+512];
  const float* wsrc = (j<12)? w1 : w2;
  int xi = (j<12)? j : j-12;
  size_t base=((size_t)xi*12+kx)*2;
  for(int io=tid;io<4096;io+=512){
    swr[io]=wsrc[(size_t)io*288+base];
    swi[io]=wsrc[(size_t)io*288+base+1];
  }
  __syncthreads();
  int b=tid>>6, o=tid&63;
  const float* xb = sx + b*128;
  float re=0.0f,im=0.0f;
  #pragma unroll 8
  for(int i=0;i<64;i++){
    float a=xb[2*i], b2=xb[2*i+1];
    float c=swr[i*64+o], d=swi[i*64+o];
    re += a*c - b2*d;
    im += a*d + b2*c;
  }
  XO[2*((size_t)m*512+tid)]  =re;
  XO[2*((size_t)m*512+tid)+1]=im;
}

// inverse DFT along H: Y[R][kx][o][{re,im}], R=b*201+h
__global__ void k_idfth(const float* __restrict__ XO, const float* __restrict__ tab,
                        float* __restrict__ Y){
  int R = blockIdx.x;
  int b = R/NN, h = R - b*NN;
  int tid=threadIdx.x;
  int kx = blockIdx.y*4 + (tid>>6);
  int o = tid&63;
  float re=0.f,im=0.f;
  #pragma unroll
  for(int j=0;j<24;j++){
    int k2=(j<12)?j:24-j;
    float sgn=(j<12)?1.0f:-1.0f;
    float2 xo = *(const float2*)(XO + 2*(((size_t)(j*12+kx)*8 + b)*64 + o));
    float2 cs = *(const float2*)(tab + (k2*NN+h)*2);
    float cc=cs.x, s2=sgn*cs.y;
    re += xo.x*cc - xo.y*s2;
    im += xo.x*s2 + xo.y*cc;
  }
  float2* yp = (float2*)(Y + ((size_t)R*12 + kx)*128) + o;
  *yp = float2{re,im};
}

// inverse C2R along W + 1/N^2: C[b][p][o] bf16
__global__ void __launch_bounds__(256) k_idftw(const float* __restrict__ Y,
        const float* __restrict__ tab, bf16* __restrict__ C){
  __shared__ float2 st[2412];
  int tid=threadIdx.x;
  for(int i=tid;i<2412;i+=256) st[i]=((const float2*)tab)[i];
  __syncthreads();
  int R = blockIdx.x;
  int wd = tid>>6, o = tid&63;
  float yr[12], yi[12];
  const float2* yb = (const float2*)(Y + (size_t)R*1536) + o;
  #pragma unroll
  for(int k=0;k<12;k++){
    float2 v = yb[(size_t)k*64];
    yr[k]=v.x; yi[k]=v.y;
  }
  int w0 = wd*51;
  int w1 = w0+51; if(w1>NN) w1=NN;
  bf16* cp = C + ((size_t)R*NN)*64 + o;
  for(int w=w0;w<w1;w++){
    float acc = yr[0];
    #pragma unroll
    for(int k=1;k<12;k++){
      float2 cs = st[k*NN+w];
      acc += 2.0f*(yr[k]*cs.x - yi[k]*cs.y);
    }
    cp[(size_t)w*64] = f2b(acc*(1.0f/40401.0f));
  }
}

// Gram partials ([p][c] layout). grid (nblk, BB, nsrc).
__global__ void __launch_bounds__(256) k_gramp(const bf16* __restrict__ s0,
        const bf16* __restrict__ s1, float* __restrict__ Gpart,
        float* __restrict__ Spart, int HR, int WR){
  __shared__ float sx[8704];
  int b = blockIdx.y, blk = blockIdx.x, z = blockIdx.z;
  const bf16* X = (z==0)? s0 : s1;
  int zb = z*BB + b;
  int npix = HR*WR;
  int tid = threadIdx.x;
  int wid = tid>>6, lane = tid&63;
  int i0 = (lane>>3)*8, j0 = (lane&7)*8;
  float acc[8][8];
  #pragma unroll
  for(int r=0;r<8;r++){
    #pragma unroll
    for(int s=0;s<8;s++) acc[r][s]=0.f;
  }
  float cs = 0.f;
  for(int tile=0;tile<8;tile++){
    int rp0 = blk*1024 + tile*128;
    __syncthreads();
    #pragma unroll
    for(int it=0;it<4;it++){
      int chunk = tid + it*256;     // 1024 chunks of 8 ch
      int k = chunk>>3, c0 = (chunk&7)*8;
      int rp = rp0+k;
      float v[8]={0,0,0,0,0,0,0,0};
      if(rp<npix){
        int gp;
        if(WR==NN) gp = rp;
        else { int hh=rp/WR, ww=rp-hh*WR; gp = hh*NN+ww; }
        s8v xv = *(const s8v*)(X + ((size_t)b*NPIX + gp)*64 + c0);
        #pragma unroll
        for(int j=0;j<8;j++) v[j]=bu2f((unsigned short)xv[j]);
      }
      #pragma unroll
      for(int j=0;j<8;j++) sx[k*68+c0+j]=v[j];
    }
    __syncthreads();
    for(int pp=0;pp<32;pp++){
      const float* row = sx + (wid*32+pp)*68;
      cs += row[lane];
      const float4* ri = (const float4*)(row + i0);
      const float4* rj = (const float4*)(row + j0);
      float4 xi0 = ri[0], xi1 = ri[1];
      float4 xj0 = rj[0], xj1 = rj[1];
      float xi[8] = {xi0.x,xi0.y,xi0.z,xi0.w, xi1.x,xi1.y,xi1.z,xi1.w};
      float xj[8] = {xj0.x,xj0.y,xj0.z,xj0.w, xj1.x,xj1.y,xj1.z,xj1.w};
      #pragma unroll
      for(int r=0;r<8;r++){
        #pragma unroll
        for(int s=0;s<8;s++) acc[r][s] += xi[r]*xj[s];
      }
    }
  }
  __syncthreads();
  float* scol = sx + 8320;
  scol[tid] = cs;
  if(wid>=2){
    float* d = sx + (tid-128)*65;
    #pragma unroll
    for(int r=0;r<8;r++){
      #pragma unroll
      for(int s=0;s<8;s++) d[r*8+s]=acc[r][s];
    }
  }
  __syncthreads();
  if(wid<2){
    const float* d = sx + tid*65;
    #pragma unroll
    for(int r=0;r<8;r++){
      #pragma unroll
      for(int s=0;s<8;s++) acc[r][s]+=d[r*8+s];
    }
  }
  if(tid<64){
    float tot = scol[tid]+scol[tid+64]+scol[tid+128]+scol[tid+192];
    Spart[((size_t)zb*GNB + blk)*64 + tid] = tot;
  }
  __syncthreads();
  if(wid==1){
    float* d = sx + (tid-64)*65;
    #pragma unroll
    for(int r=0;r<8;r++){
      #pragma unroll
      for(int s=0;s<8;s++) d[r*8+s]=acc[r][s];
    }
  }
  __syncthreads();
  if(wid==0){
    const float* d = sx + tid*65;
    #pragma unroll
    for(int r=0;r<8;r++){
      #pragma unroll
      for(int s=0;s<8;s++) acc[r][s]+=d[r*8+s];
    }
    float* g = Gpart + ((size_t)zb*GNB + blk)*4096;
    #pragma unroll
    for(int r=0;r<8;r++){
      #pragma unroll
      for(int s=0;s<8;s++) g[(i0+r)*64 + (j0+s)] = acc[r][s];
    }
  }
}

__global__ void k_gramr(const float* __restrict__ Gpart, const float* __restrict__ Spart,
                        float* __restrict__ G, float* __restrict__ S, int nblk){
  int zb = blockIdx.x; int tid = threadIdx.x;
  float a[16];
  #pragma unroll
  for(int e=0;e<16;e++) a[e]=0.f;
  for(int k=0;k<nblk;k++){
    const float* g = Gpart + ((size_t)zb*GNB + k)*4096 + tid*16;
    #pragma unroll
    for(int e=0;e<16;e++) a[e]+=g[e];
  }
  float* go = G + (size_t)zb*4096 + tid*16;
  #pragma unroll
  for(int e=0;e<16;e++) go[e]=a[e];
  if(tid<64){
    float s=0.f;
    for(int k=0;k<nblk;k++) s += Spart[((size_t)zb*GNB + k)*64 + tid];
    S[(size_t)zb*64 + tid]=s;
  }
}

// GN stats from Gram, weights rounded to bf16 (match MFMA arithmetic)
__global__ void k_stats64(const float* __restrict__ W, const float* __restrict__ bias,
                          const float* __restrict__ G, const float* __restrict__ S,
                          float* __restrict__ stat, float Nf){
  __shared__ float rs[256], rq[256];
  int b=blockIdx.x, t=threadIdx.x;
  int o = t&63, sl = t>>6;
  float w[64];
  #pragma unroll
  for(int j2=0;j2<64;j2++) w[j2]=bu2f(f2bu(W[(size_t)o*64+j2]));
  float wl[16];
  #pragma unroll
  for(int r=0;r<16;r++) wl[r]=w[sl*16+r];
  const float* Gr = G + (size_t)b*4096 + (size_t)(sl*16)*64;
  float quad=0.f;
  #pragma unroll
  for(int r=0;r<16;r++){
    const float* gr = Gr + r*64;
    float tt=0.f;
    #pragma unroll
    for(int j2=0;j2<64;j2++) tt += gr[j2]*w[j2];
    quad += wl[r]*tt;
  }
  float dot=0.f;
  #pragma unroll
  for(int j2=0;j2<64;j2++) dot += w[j2]*S[b*64+j2];
  float bo = bias[o];
  float sm = (sl==0)? (dot + Nf*bo) : 0.f;
  float sq = quad + ((sl==0)? (2.f*bo*dot + Nf*bo*bo) : 0.f);
  rs[t]=sm; rq[t]=sq;
  __syncthreads();
  if(t<64){
    float s2 = rs[t]+rs[t+64]+rs[t+128]+rs[t+192];
    float q2 = rq[t]+rq[t+64]+rq[t+128]+rq[t+192];
    for(int off=16;off>0;off>>=1){
      s2 += __shfl_down(s2,off,32);
      q2 += __shfl_down(q2,off,32);
    }
    if((t&31)==0){
      int g=t>>5;
      float invN = 1.f/(Nf*32.f);
      float mean = s2*invN;
      float var = q2*invN - mean*mean;
      stat[b*4+g*2]   = mean;
      stat[b*4+g*2+1] = rsqrtf(fmaxf(var,0.f)+1e-5f);
    }
  }
}

__global__ void k_stats256(const float* __restrict__ W, const float* __restrict__ bias,
                           const float* __restrict__ G, const float* __restrict__ S,
                           float* __restrict__ stat, float Nf){
  __shared__ float red[8];
  int b=blockIdx.x, t=threadIdx.x;
  float w[64];
  #pragma unroll
  for(int j2=0;j2<64;j2++) w[j2]=bu2f(f2bu(W[(size_t)t*64+j2]));
  const float* Gb = G + (size_t)b*4096;
  float quad=0.f;
  #pragma unroll
  for(int i=0;i<64;i++){
    const float* gr = Gb + i*64;
    float tt=0.f;
    #pragma unroll
    for(int j2=0;j2<64;j2++) tt += gr[j2]*w[j2];
    quad += w[i]*tt;
  }
  float dot=0.f;
  #pragma unroll
  for(int j2=0;j2<64;j2++) dot += w[j2]*S[b*64+j2];
  float bo=bias[t];
  float sm = dot + Nf*bo;
  float sq = quad + 2.f*bo*dot + Nf*bo*bo;
  for(int off=32;off>0;off>>=1){
    sm += __shfl_down(sm,off,64);
    sq += __shfl_down(sq,off,64);
  }
  int wid=t>>6;
  if((t&63)==0){ red[wid*2]=sm; red[wid*2+1]=sq; }
  __syncthreads();
  if(t<2){
    float smt = red[t*4+0]+red[t*4+2];
    float sqt = red[t*4+1]+red[t*4+3];
    float invN = 1.f/(Nf*128.f);
    float mean = smt*invN;
    float var = sqt*invN - mean*mean;
    stat[b*4+t*2]   = mean;
    stat[b*4+t*2+1] = rsqrtf(fmaxf(var,0.f)+1e-5f);
  }
}

// MFMA fused layer: x1 = m2w@gelu(GN(m1w@Cb+m1b)) + m2b ; x2 = GN(ww@A+wb);
// A = gelu?(x1+x2). Wave = 64 px, block = 256 px.
__global__ void __launch_bounds__(256) k_fuse(const bf16* __restrict__ Cb,
    bf16* __restrict__ A,
    const float* __restrict__ m1w, const float* __restrict__ m1b,
    const float* __restrict__ mg,  const float* __restrict__ mbt,
    const float* __restrict__ m2w, const float* __restrict__ m2b,
    const float* __restrict__ wwk, const float* __restrict__ wbk,
    const float* __restrict__ ng,  const float* __restrict__ nb,
    const float* __restrict__ tstat, const float* __restrict__ ustat, int last){
  __shared__ unsigned short vlds[4][64][72];
  int tid=threadIdx.x;
  int wid=tid>>6, l=tid&63;
  int m_=l&15, g=l>>4;
  int b=blockIdx.y;
  int p0=blockIdx.x*256 + wid*64;
  const bf16* cbb = Cb + (size_t)b*NPIX*64;
  const bf16* ab  = A  + (size_t)b*NPIX*64;

  s8v af[4][2];
  f32x4 acc[4][4];

  // ---- GEMM1: t = m1w @ Cb + m1b ----
  #pragma unroll
  for(int mt=0;mt<4;mt++){
    #pragma unroll
    for(int kh=0;kh<2;kh++){
      const float* wp = m1w + (size_t)(16*mt+m_)*64 + 32*kh + 8*g;
      s8v f;
      #pragma unroll
      for(int j=0;j<8;j++) f[j]=(short)f2bu(wp[j]);
      af[mt][kh]=f;
    }
    float4 b4 = *(const float4*)(m1b + 16*mt + 4*g);
    #pragma unroll
    for(int nt=0;nt<4;nt++) acc[mt][nt]=f32x4{b4.x,b4.y,b4.z,b4.w};
  }
  #pragma unroll
  for(int nt=0;nt<4;nt++){
    int p = p0 + 16*nt + m_;
    int pc = p<NPIX? p : NPIX-1;
    const s8v* xb = (const s8v*)(cbb + (size_t)pc*64);
    s8v b0 = xb[g], b1 = xb[4+g];
    #pragma unroll
    for(int mt=0;mt<4;mt++){
      acc[mt][nt]=__builtin_amdgcn_mfma_f32_16x16x32_bf16(af[mt][0],b0,acc[mt][nt],0,0,0);
      acc[mt][nt]=__builtin_amdgcn_mfma_f32_16x16x32_bf16(af[mt][1],b1,acc[mt][nt],0,0,0);
    }
  }
  // ---- epilogue1: GN+gelu -> v (wave-private LDS) ----
  {
    float tm0=tstat[b*4],tr0=tstat[b*4+1],tm1=tstat[b*4+2],tr1=tstat[b*4+3];
    #pragma unroll
    for(int mt=0;mt<4;mt++){
      float4 g4 = *(const float4*)(mg  + 16*mt + 4*g);
      float4 t4 = *(const float4*)(mbt + 16*mt + 4*g);
      float mn = (mt<2)? tm0 : tm1;
      float rs = (mt<2)? tr0 : tr1;
      #pragma unroll
      for(int nt=0;nt<4;nt++){
        int pl = 16*nt + m_;
        f32x4 t = acc[mt][nt];
        float v0 = gelu_f((t[0]-mn)*rs*g4.x + t4.x);
        float v1 = gelu_f((t[1]-mn)*rs*g4.y + t4.y);
        float v2 = gelu_f((t[2]-mn)*rs*g4.z + t4.z);
        float v3 = gelu_f((t[3]-mn)*rs*g4.w + t4.w);
        uint2 pk;
        pk.x = (unsigned)f2bu(v0) | ((unsigned)f2bu(v1)<<16);
        pk.y = (unsigned)f2bu(v2) | ((unsigned)f2bu(v3)<<16);
        *(uint2*)&vlds[wid][pl][16*mt+4*g] = pk;
      }
    }
  }
  __syncthreads();
  // ---- GEMM3: u = ww @ A + wb ----
  #pragma unroll
  for(int mt=0;mt<4;mt++){
    #pragma unroll
    for(int kh=0;kh<2;kh++){
      const float* wp = wwk + (size_t)(16*mt+m_)*64 + 32*kh + 8*g;
      s8v f;
      #pragma unroll
      for(int j=0;j<8;j++) f[j]=(short)f2bu(wp[j]);
      af[mt][kh]=f;
    }
    float4 b4 = *(const float4*)(wbk + 16*mt + 4*g);
    #pragma unroll
    for(int nt=0;nt<4;nt++) acc[mt][nt]=f32x4{b4.x,b4.y,b4.z,b4.w};
  }
  #pragma unroll
  for(int nt=0;nt<4;nt++){
    int p = p0 + 16*nt + m_;
    int pc = p<NPIX? p : NPIX-1;
    const s8v* xb = (const s8v*)(ab + (size_t)pc*64);
    s8v b0 = xb[g], b1 = xb[4+g];
    #pragma unroll
    for(int mt=0;mt<4;mt++){
      acc[mt][nt]=__builtin_amdgcn_mfma_f32_16x16x32_bf16(af[mt][0],b0,acc[mt][nt],0,0,0);
      acc[mt][nt]=__builtin_amdgcn_mfma_f32_16x16x32_bf16(af[mt][1],b1,acc[mt][nt],0,0,0);
    }
  }
  // ---- epilogue3: acc = m2b + GN(u) ----
  {
    float um0=ustat[b*4],ur0=ustat[b*4+1],um1=ustat[b*4+2],ur1=ustat[b*4+3];
    #pragma unroll
    for(int mt=0;mt<4;mt++){
      float4 n4 = *(const float4*)(ng  + 16*mt + 4*g);
      float4 nb4= *(const float4*)(nb  + 16*mt + 4*g);
      float4 m24= *(const float4*)(m2b + 16*mt + 4*g);
      float mn = (mt<2)? um0 : um1;
      float rs = (mt<2)? ur0 : ur1;
      #pragma unroll
      for(int nt=0;nt<4;nt++){
        f32x4 u = acc[mt][nt];
        u[0] = m24.x + (u[0]-mn)*rs*n4.x + nb4.x;
        u[1] = m24.y + (u[1]-mn)*rs*n4.y + nb4.y;
        u[2] = m24.z + (u[2]-mn)*rs*n4.z + nb4.z;
        u[3] = m24.w + (u[3]-mn)*rs*n4.w + nb4.w;
        acc[mt][nt]=u;
      }
    }
  }
  // ---- GEMM2: acc += m2w @ v ----
  #pragma unroll
  for(int mt=0;mt<4;mt++){
    #pragma unroll
    for(int kh=0;kh<2;kh++){
      const float* wp = m2w + (size_t)(16*mt+m_)*64 + 32*kh + 8*g;
      s8v f;
      #pragma unroll
      for(int j=0;j<8;j++) f[j]=(short)f2bu(wp[j]);
      af[mt][kh]=f;
    }
  }
  #pragma unroll
  for(int nt=0;nt<4;nt++){
    int pl = 16*nt + m_;
    const s8v* vp = (const s8v*)&vlds[wid][pl][0];
    s8v b0 = vp[g], b1 = vp[4+g];
    #pragma unroll
    for(int mt=0;mt<4;mt++){
      acc[mt][nt]=__builtin_amdgcn_mfma_f32_16x16x32_bf16(af[mt][0],b0,acc[mt][nt],0,0,0);
      acc[mt][nt]=__builtin_amdgcn_mfma_f32_16x16x32_bf16(af[mt][1],b1,acc[mt][nt],0,0,0);
    }
  }
  // ---- final: h = gelu?(x1+x2) -> A ----
  #pragma unroll
  for(int nt=0;nt<4;nt++){
    int p = p0 + 16*nt + m_;
    if(p>=NPIX) continue;
    bf16* dp = A + ((size_t)b*NPIX + p)*64;
    #pragma unroll
    for(int mt=0;mt<4;mt++){
      f32x4 h = acc[mt][nt];
      float h0=h[0],h1=h[1],h2=h[2],h3=h[3];
      if(!last){ h0=gelu_f(h0); h1=gelu_f(h1); h2=gelu_f(h2); h3=gelu_f(h3); }
      uint2 pk;
      pk.x = (unsigned)f2bu(h0) | ((unsigned)f2bu(h1)<<16);
      pk.y = (unsigned)f2bu(h2) | ((unsigned)f2bu(h3)<<16);
      *(uint2*)(dp + 16*mt + 4*g) = pk;
    }
  }
}

// MFMA head: out = q2w @ gelu(GN(q1w@h_crop+q1b)) + q2b
__global__ void __launch_bounds__(256) k_qout(const bf16* __restrict__ A,
    const float* __restrict__ q1w, const float* __restrict__ q1b,
    const float* __restrict__ qg, const float* __restrict__ qbt,
    const float* __restrict__ q2w, const float* __restrict__ q2b,
    const float* __restrict__ qstat, float* __restrict__ out){
  int tid=threadIdx.x;
  int wid=tid>>6, l=tid&63;
  int m_=l&15, g=l>>4;
  int b=blockIdx.y;
  int p0=blockIdx.x*256 + wid*64;
  s8v bfr[4][2];
  #pragma unroll
  for(int nt=0;nt<4;nt++){
    int p = p0 + 16*nt + m_;
    int hh=p/SS, ww2=p-hh*SS;
    size_t gp = (size_t)hh*NN + ww2;
    const s8v* xb = (const s8v*)(A + ((size_t)b*NPIX + gp)*64);
    bfr[nt][0]=xb[g]; bfr[nt][1]=xb[4+g];
  }
  float m0=qstat[b*4],r0=qstat[b*4+1],m1=qstat[b*4+2],r1=qstat[b*4+3];
  float outv[4]={0.f,0.f,0.f,0.f};
  for(int oc=0;oc<4;oc++){
    s8v af[4][2];
    f32x4 acc[4][4];
    #pragma unroll
    for(int mt=0;mt<4;mt++){
      #pragma unroll
      for(int kh=0;kh<2;kh++){
        const float* wp = q1w + (size_t)(64*oc+16*mt+m_)*64 + 32*kh + 8*g;
        s8v f;
        #pragma unroll
        for(int j=0;j<8;j++) f[j]=(short)f2bu(wp[j]);
        af[mt][kh]=f;
      }
      float4 b4 = *(const float4*)(q1b + 64*oc + 16*mt + 4*g);
      #pragma unroll
      for(int nt=0;nt<4;nt++) acc[mt][nt]=f32x4{b4.x,b4.y,b4.z,b4.w};
    }
    #pragma unroll
    for(int nt=0;nt<4;nt++){
      #pragma unroll
      for(int mt=0;mt<4;mt++){
        acc[mt][nt]=__builtin_amdgcn_mfma_f32_16x16x32_bf16(af[mt][0],bfr[nt][0],acc[mt][nt],0,0,0);
        acc[mt][nt]=__builtin_amdgcn_mfma_f32_16x16x32_bf16(af[mt][1],bfr[nt][1],acc[mt][nt],0,0,0);
      }
    }
    float mn = (oc<2)? m0 : m1;
    float rs = (oc<2)? r0 : r1;
    #pragma unroll
    for(int mt=0;mt<4;mt++){
      float4 g4 = *(const float4*)(qg  + 64*oc + 16*mt + 4*g);
      float4 t4 = *(const float4*)(qbt + 64*oc + 16*mt + 4*g);
      float4 w4 = *(const float4*)(q2w + 64*oc + 16*mt + 4*g);
      #pragma unroll
      for(int nt=0;nt<4;nt++){
        f32x4 t = acc[mt][nt];
        outv[nt] += gelu_f((t[0]-mn)*rs*g4.x + t4.x)*w4.x;
        outv[nt] += gelu_f((t[1]-mn)*rs*g4.y + t4.y)*w4.y;
        outv[nt] += gelu_f((t[2]-mn)*rs*g4.z + t4.z)*w4.z;
        outv[nt] += gelu_f((t[3]-mn)*rs*g4.w + t4.w)*w4.w;
      }
    }
  }
  float qb0 = q2b[0];
  #pragma unroll
  for(int nt=0;nt<4;nt++){
    float s = outv[nt];
    s += __shfl_xor(s,16,64);
    s += __shfl_xor(s,32,64);
    if(g==0){
      int p = p0 + 16*nt + m_;
      out[(size_t)b*QPIX + p] = s + qb0;
    }
  }
}

extern "C" void kernel_launch(void* const* d_in, const int* in_sizes, int n_in,
                              void* d_out, int out_size, void* d_ws, size_t ws_size,
                              hipStream_t stream){
  const float* x   = (const float*)d_in[0];
  const float* Wp  = (const float*)d_in[1];
  const float* bp  = (const float*)d_in[2];
  const float* sw1 = (const float*)d_in[3];
  const float* sw2 = (const float*)d_in[4];
  const float* m1w = (const float*)d_in[5];
  const float* m1b = (const float*)d_in[6];
  const float* mg  = (const float*)d_in[7];
  const float* mbt = (const float*)d_in[8];
  const float* m2w = (const float*)d_in[9];
  const float* m2b = (const float*)d_in[10];
  const float* ww  = (const float*)d_in[11];
  const float* wb  = (const float*)d_in[12];
  const float* ng  = (const float*)d_in[13];
  const float* nb  = (const float*)d_in[14];
  const float* q1w = (const float*)d_in[15];
  const float* q1b = (const float*)d_in[16];
  const float* qg  = (const float*)d_in[17];
  const float* qbt = (const float*)d_in[18];
  const float* q2w = (const float*)d_in[19];
  const float* q2b = (const float*)d_in[20];
  float* out = (float*)d_out;

  char* w8 = (char*)d_ws;
  const size_t ACT_B = (size_t)64*BB*NPIX*sizeof(bf16);   // 41,370,624
  bf16*  A    = (bf16*)(w8);
  bf16*  Cb   = (bf16*)(w8 + ACT_B);
  float* SPEC = (float*)(w8 + 2*ACT_B);                    // XW / Y / Gram-partial overlay
  float* XF   = (float*)(w8 + 2*ACT_B + 9879552);
  float* XO   = (float*)(w8 + 2*ACT_B + 9879552 + 1179648);
  float* TB   = (float*)(w8 + 2*ACT_B + 9879552 + 2*1179648);
  char*  g8   = w8 + 2*ACT_B + 9879552 + 2*1179648 + 20992;
  float* Gfin = (float*)g8;
  float* Sfin = Gfin + 16*4096;
  float* TSTAT= (float*)(g8 + (size_t)(32768+512)*2*4);
  float* USTAT= TSTAT + 32;
  float* QSTAT= USTAT + 32;
  float* Gpart = SPEC;
  float* Spart = Gpart + (size_t)16*GNB*4096;
  size_t needed = (size_t)(2*ACT_B) + 9879552 + 2*1179648 + 20992
                + (size_t)(32768+512)*2*4 + 3*32*4;
  if(ws_size < needed) return;

  k_tab<<<11,256,0,stream>>>(TB);
  k_encoder<<<dim3(158,BB),256,0,stream>>>(x, Wp, bp, A);

  for(int l=0;l<4;l++){
    const float* sw1l = sw1 + (size_t)l*1179648;
    const float* sw2l = sw2 + (size_t)l*1179648;
    k_dftw<<<402,256,0,stream>>>(A, TB, SPEC);
    k_dfth<<<576,256,0,stream>>>(SPEC, TB, XF);
    k_modemix<<<288,512,0,stream>>>(XF, sw1l, sw2l, XO);
    k_idfth<<<dim3(1608,3),256,0,stream>>>(XO, TB, SPEC);
    k_idftw<<<1608,256,0,stream>>>(SPEC, TB, Cb);
    k_gramp<<<dim3(GNB,BB,2),256,0,stream>>>(Cb, A, Gpart, Spart, NN, NN);
    k_gramr<<<16,256,0,stream>>>(Gpart, Spart, Gfin, Sfin, GNB);
    k_stats64<<<BB,256,0,stream>>>(m1w + (size_t)l*4096, m1b + l*64, Gfin, Sfin, TSTAT, (float)NPIX);
    k_stats64<<<BB,256,0,stream>>>(ww  + (size_t)l*4096, wb  + l*64, Gfin + (size_t)8*4096, Sfin + 8*64, USTAT, (float)NPIX);
    k_fuse<<<dim3(158,BB),256,0,stream>>>(Cb, A,
          m1w + (size_t)l*4096, m1b + l*64, mg + l*64, mbt + l*64,
          m2w + (size_t)l*4096, m2b + l*64,
          ww  + (size_t)l*4096, wb  + l*64, ng + l*64, nb + l*64,
          TSTAT, USTAT, (l==3)?1:0);
  }

  k_gramp<<<dim3(36,BB,1),256,0,stream>>>(A, A, Gpart, Spart, SS, SS);
  k_gramr<<<BB,256,0,stream>>>(Gpart, Spart, Gfin, Sfin, 36);
  k_stats256<<<BB,256,0,stream>>>(q1w, q1b, Gfin, Sfin, QSTAT, (float)QPIX);
  k_qout<<<dim3(144,BB),256,0,stream>>>(A, q1w, q1b, qg, qbt, q2w, q2b, QSTAT, out);
}

// Round 6
// 1997.810 us; speedup vs baseline: 9.1594x; 1.3038x over previous
//
#include <hip/hip_runtime.h>
#include <hip/hip_bf16.h>
#include <math.h>

// FNO2d: B=8, S=192, pad->201x201, C=64, modes 12x12, 4 layers.
// Pixel-major activations [b][p][c] + MFMA conv GEMMs.
// Encoder = separable pos-enc tables (no per-pixel trig).

#define NN 201
#define SS 192
#define NPIX 40401
#define QPIX 36864
#define BB 8
#define GNB 40
#define XWPL 1234944     // 1608*12*64 (re/im plane stride in floats)
#define PI_F 3.14159265358979323846f

typedef __hip_bfloat16 bf16;
typedef __attribute__((ext_vector_type(8))) short s8v;
typedef __attribute__((ext_vector_type(4))) float f32x4;

__device__ __forceinline__ float gelu_f(float x){
  return 0.5f*x*(1.0f+erff(x*0.7071067811865476f));
}
__device__ __forceinline__ float b2f(bf16 v){ return __bfloat162float(v); }
__device__ __forceinline__ bf16  f2b(float v){ return __float2bfloat16(v); }
__device__ __forceinline__ unsigned short f2bu(float x){
  bf16 h = __float2bfloat16(x);
  unsigned short u; __builtin_memcpy(&u,&h,2); return u;
}
__device__ __forceinline__ float bu2f(unsigned short u){
  unsigned int x = ((unsigned int)u)<<16; float f; __builtin_memcpy(&f,&x,4); return f;
}

// tab[k][n]: cos/sin(2*pi*k*n/201), k=0..12, exact mod-201 reduction
__global__ void k_tab(float* __restrict__ tab){
  int t = blockIdx.x*blockDim.x+threadIdx.x;
  if(t>=13*NN) return;
  int k=t/NN, n=t-k*NN;
  int m=(k*n)%NN;
  float ang = (2.0f*PI_F/201.0f)*(float)m;
  tab[2*t]   = cosf(ang);
  tab[2*t+1] = sinf(ang);
}

// Separable encoder tables. grid (192, 2), 64 threads.
// axis 0 (x/hh): Ux[i][c] = bp[c] + gx*Wp[1][c] + sum_l cos*Wp[3+2l][c] + sin*Wp[23+2l][c]
// axis 1 (y/ww): Uy[j][c] =         gy*Wp[2][c] + sum_l cos*Wp[4+2l][c] + sin*Wp[24+2l][c]
__global__ void k_pretab(const float* __restrict__ Wp, const float* __restrict__ bp,
                         float* __restrict__ Ux, float* __restrict__ Uy){
  int i = blockIdx.x;
  int ax = blockIdx.y;
  int c = threadIdx.x;
  float g = (float)i*(1.0f/191.0f);
  float acc;
  if(ax==0) acc = bp[c] + g*Wp[64+c];
  else      acc = g*Wp[128+c];
  int cosBase = (ax==0)? 3 : 4;
  int sinBase = (ax==0)? 23 : 24;
  #pragma unroll
  for(int l=0;l<10;l++){
    float f = PI_F*(float)(1<<l);
    float sv,cv;
    sincosf(g*f,&sv,&cv);
    acc += cv*Wp[(cosBase+2*l)*64+c] + sv*Wp[(sinBase+2*l)*64+c];
  }
  float* U = (ax==0)? Ux : Uy;
  U[i*64+c] = acc;
}

// encoder: A[b][p][c] = x*Wp0[c] + Ux[hh][c] + Uy[ww][c]; zeros in pad.
__global__ void k_encoder(const float* __restrict__ x, const float* __restrict__ Wp,
                          const float* __restrict__ Ux, const float* __restrict__ Uy,
                          bf16* __restrict__ A){
  int tid=threadIdx.x;
  int p = blockIdx.x*256+tid;
  if(p>=NPIX) return;
  int b = blockIdx.y;
  uint4* dst = (uint4*)(A + ((size_t)b*NPIX + p)*64);
  int hh=p/NN, ww=p-hh*NN;
  if(hh>=SS || ww>=SS){
    uint4 z = {0,0,0,0};
    #pragma unroll
    for(int i=0;i<8;i++) dst[i]=z;
    return;
  }
  float xv = x[((size_t)b*SS+hh)*SS+ww];
  const float4* ux = (const float4*)(Ux + hh*64);
  const float4* uy = (const float4*)(Uy + ww*64);
  const float4* w0 = (const float4*)Wp;
  #pragma unroll
  for(int i=0;i<8;i++){
    float4 a0 = ux[2*i],   a1 = ux[2*i+1];
    float4 b0 = uy[2*i],   b1 = uy[2*i+1];
    float4 c0 = w0[2*i],   c1 = w0[2*i+1];
    float v0=xv*c0.x+a0.x+b0.x, v1=xv*c0.y+a0.y+b0.y;
    float v2=xv*c0.z+a0.z+b0.z, v3=xv*c0.w+a0.w+b0.w;
    float v4=xv*c1.x+a1.x+b1.x, v5=xv*c1.y+a1.y+b1.y;
    float v6=xv*c1.z+a1.z+b1.z, v7=xv*c1.w+a1.w+b1.w;
    uint4 v;
    v.x = (unsigned)f2bu(v0) | ((unsigned)f2bu(v1)<<16);
    v.y = (unsigned)f2bu(v2) | ((unsigned)f2bu(v3)<<16);
    v.z = (unsigned)f2bu(v4) | ((unsigned)f2bu(v5)<<16);
    v.w = (unsigned)f2bu(v6) | ((unsigned)f2bu(v7)<<16);
    dst[i]=v;
  }
}

// DFT along W. Wave per row R=b*201+h, lane=c. XW[re/im][R][kx][c].
__global__ void __launch_bounds__(256) k_dftw(const bf16* __restrict__ A,
        const float* __restrict__ tab, float* __restrict__ XW){
  __shared__ float2 st[2412];
  int tid=threadIdx.x;
  for(int i=tid;i<2412;i+=256) st[i]=((const float2*)tab)[i];
  __syncthreads();
  int R = blockIdx.x*4 + (tid>>6);   // 402 blocks -> 1608 rows
  int l = tid&63;
  const bf16* base = A + ((size_t)R*NN)*64 + l;
  float ar0=0.f;
  float ar[11], ai[11];
  #pragma unroll
  for(int k=0;k<11;k++){ ar[k]=0.f; ai[k]=0.f; }
  for(int w=0;w<NN;w++){
    float a = b2f(base[(size_t)w*64]);
    ar0 += a;
    #pragma unroll
    for(int k=0;k<11;k++){
      float2 cs = st[(k+1)*NN+w];
      ar[k] += a*cs.x;
      ai[k] += a*cs.y;
    }
  }
  float* xre = XW + ((size_t)R*12)*64 + l;
  float* xim = xre + XWPL;
  xre[0]=ar0; xim[0]=0.f;
  #pragma unroll
  for(int k=0;k<11;k++){
    xre[(size_t)(k+1)*64] = ar[k];
    xim[(size_t)(k+1)*64] = -ai[k];
  }
}

// DFT along H: XF[m][b*64+c][{re,im}]; m=j*12+kx
__global__ void k_dfth(const float* __restrict__ XW, const float* __restrict__ tab,
                       float* __restrict__ XF){
  __shared__ float2 st[NN];
  int bx = blockIdx.x;               // 576 = 8*24*3
  int b = bx/72, rem = bx - b*72;
  int j = rem/3, q = rem - (rem/3)*3;
  int tid=threadIdx.x;
  int kx = q*4 + (tid>>6);
  int c = tid&63;
  int k2 = (j<12)? j : 24-j;
  float sgn = (j<12)? -1.0f : 1.0f;
  for(int i=tid;i<NN;i+=256) st[i]=((const float2*)tab)[k2*NN+i];
  __syncthreads();
  const float* re = XW + (((size_t)b*NN)*12 + kx)*64 + c;
  const float* im = re + XWPL;
  float sre=0.f,sim=0.f;
  for(int h=0;h<NN;h++){
    float a = re[(size_t)h*768];
    float b2 = im[(size_t)h*768];
    float2 cs = st[h];
    float cc=cs.x, s2=sgn*cs.y;
    sre += a*cc - b2*s2;
    sim += a*s2 + b2*cc;
  }
  int m = j*12+kx;
  XF[(size_t)m*1024 + (b*64+c)*2]   = sre;
  XF[(size_t)m*1024 + (b*64+c)*2+1] = sim;
}

// per-mode 64x64 complex mix
__global__ void __launch_bounds__(512) k_modemix(const float* __restrict__ XF,
     const float* __restrict__ w1, const float* __restrict__ w2,
     float* __restrict__ XO){
  __shared__ float sx[1024];
  __shared__ float swr[4096], swi[4096];
  int m=blockIdx.x;
  int j=m/12, kx=m-j*12;
  int tid=threadIdx.x;
  sx[tid]     = XF[(size_t)m*1024+tid];
  sx[tid+512] = XF[(size_t)m*1024+tid+512];
  const float* wsrc = (j<12)? w1 : w2;
  int xi = (j<12)? j : j-12;
  size_t base=((size_t)xi*12+kx)*2;
  for(int io=tid;io<4096;io+=512){
    swr[io]=wsrc[(size_t)io*288+base];
    swi[io]=wsrc[(size_t)io*288+base+1];
  }
  __syncthreads();
  int b=tid>>6, o=tid&63;
  const float* xb = sx + b*128;
  float re=0.0f,im=0.0f;
  #pragma unroll 8
  for(int i=0;i<64;i++){
    float a=xb[2*i], b2=xb[2*i+1];
    float c=swr[i*64+o], d=swi[i*64+o];
    re += a*c - b2*d;
    im += a*d + b2*c;
  }
  XO[2*((size_t)m*512+tid)]  =re;
  XO[2*((size_t)m*512+tid)+1]=im;
}

// inverse DFT along H: Y[R][kx][o][{re,im}], R=b*201+h
__global__ void k_idfth(const float* __restrict__ XO, const float* __restrict__ tab,
                        float* __restrict__ Y){
  int R = blockIdx.x;
  int b = R/NN, h = R - b*NN;
  int tid=threadIdx.x;
  int kx = blockIdx.y*4 + (tid>>6);
  int o = tid&63;
  float re=0.f,im=0.f;
  #pragma unroll
  for(int j=0;j<24;j++){
    int k2=(j<12)?j:24-j;
    float sgn=(j<12)?1.0f:-1.0f;
    float2 xo = *(const float2*)(XO + 2*(((size_t)(j*12+kx)*8 + b)*64 + o));
    float2 cs = *(const float2*)(tab + (k2*NN+h)*2);
    float cc=cs.x, s2=sgn*cs.y;
    re += xo.x*cc - xo.y*s2;
    im += xo.x*s2 + xo.y*cc;
  }
  float2* yp = (float2*)(Y + ((size_t)R*12 + kx)*128) + o;
  *yp = float2{re,im};
}

// inverse C2R along W + 1/N^2: C[b][p][o] bf16
__global__ void __launch_bounds__(256) k_idftw(const float* __restrict__ Y,
        const float* __restrict__ tab, bf16* __restrict__ C){
  __shared__ float2 st[2412];
  int tid=threadIdx.x;
  for(int i=tid;i<2412;i+=256) st[i]=((const float2*)tab)[i];
  __syncthreads();
  int R = blockIdx.x;
  int wd = tid>>6, o = tid&63;
  float yr[12], yi[12];
  const float2* yb = (const float2*)(Y + (size_t)R*1536) + o;
  #pragma unroll
  for(int k=0;k<12;k++){
    float2 v = yb[(size_t)k*64];
    yr[k]=v.x; yi[k]=v.y;
  }
  int w0 = wd*51;
  int w1 = w0+51; if(w1>NN) w1=NN;
  bf16* cp = C + ((size_t)R*NN)*64 + o;
  for(int w=w0;w<w1;w++){
    float acc = yr[0];
    #pragma unroll
    for(int k=1;k<12;k++){
      float2 cs = st[k*NN+w];
      acc += 2.0f*(yr[k]*cs.x - yi[k]*cs.y);
    }
    cp[(size_t)w*64] = f2b(acc*(1.0f/40401.0f));
  }
}

// Gram partials ([p][c] layout). grid (nblk, BB, nsrc).
__global__ void __launch_bounds__(256) k_gramp(const bf16* __restrict__ s0,
        const bf16* __restrict__ s1, float* __restrict__ Gpart,
        float* __restrict__ Spart, int HR, int WR){
  __shared__ float sx[8704];
  int b = blockIdx.y, blk = blockIdx.x, z = blockIdx.z;
  const bf16* X = (z==0)? s0 : s1;
  int zb = z*BB + b;
  int npix = HR*WR;
  int tid = threadIdx.x;
  int wid = tid>>6, lane = tid&63;
  int i0 = (lane>>3)*8, j0 = (lane&7)*8;
  float acc[8][8];
  #pragma unroll
  for(int r=0;r<8;r++){
    #pragma unroll
    for(int s=0;s<8;s++) acc[r][s]=0.f;
  }
  float cs = 0.f;
  for(int tile=0;tile<8;tile++){
    int rp0 = blk*1024 + tile*128;
    __syncthreads();
    #pragma unroll
    for(int it=0;it<4;it++){
      int chunk = tid + it*256;
      int k = chunk>>3, c0 = (chunk&7)*8;
      int rp = rp0+k;
      float v[8]={0,0,0,0,0,0,0,0};
      if(rp<npix){
        int gp;
        if(WR==NN) gp = rp;
        else { int hh=rp/WR, ww=rp-hh*WR; gp = hh*NN+ww; }
        s8v xv = *(const s8v*)(X + ((size_t)b*NPIX + gp)*64 + c0);
        #pragma unroll
        for(int j=0;j<8;j++) v[j]=bu2f((unsigned short)xv[j]);
      }
      #pragma unroll
      for(int j=0;j<8;j++) sx[k*68+c0+j]=v[j];
    }
    __syncthreads();
    for(int pp=0;pp<32;pp++){
      const float* row = sx + (wid*32+pp)*68;
      cs += row[lane];
      const float4* ri = (const float4*)(row + i0);
      const float4* rj = (const float4*)(row + j0);
      float4 xi0 = ri[0], xi1 = ri[1];
      float4 xj0 = rj[0], xj1 = rj[1];
      float xi[8] = {xi0.x,xi0.y,xi0.z,xi0.w, xi1.x,xi1.y,xi1.z,xi1.w};
      float xj[8] = {xj0.x,xj0.y,xj0.z,xj0.w, xj1.x,xj1.y,xj1.z,xj1.w};
      #pragma unroll
      for(int r=0;r<8;r++){
        #pragma unroll
        for(int s=0;s<8;s++) acc[r][s] += xi[r]*xj[s];
      }
    }
  }
  __syncthreads();
  float* scol = sx + 8320;
  scol[tid] = cs;
  if(wid>=2){
    float* d = sx + (tid-128)*65;
    #pragma unroll
    for(int r=0;r<8;r++){
      #pragma unroll
      for(int s=0;s<8;s++) d[r*8+s]=acc[r][s];
    }
  }
  __syncthreads();
  if(wid<2){
    const float* d = sx + tid*65;
    #pragma unroll
    for(int r=0;r<8;r++){
      #pragma unroll
      for(int s=0;s<8;s++) acc[r][s]+=d[r*8+s];
    }
  }
  if(tid<64){
    float tot = scol[tid]+scol[tid+64]+scol[tid+128]+scol[tid+192];
    Spart[((size_t)zb*GNB + blk)*64 + tid] = tot;
  }
  __syncthreads();
  if(wid==1){
    float* d = sx + (tid-64)*65;
    #pragma unroll
    for(int r=0;r<8;r++){
      #pragma unroll
      for(int s=0;s<8;s++) d[r*8+s]=acc[r][s];
    }
  }
  __syncthreads();
  if(wid==0){
    const float* d = sx + tid*65;
    #pragma unroll
    for(int r=0;r<8;r++){
      #pragma unroll
      for(int s=0;s<8;s++) acc[r][s]+=d[r*8+s];
    }
    float* g = Gpart + ((size_t)zb*GNB + blk)*4096;
    #pragma unroll
    for(int r=0;r<8;r++){
      #pragma unroll
      for(int s=0;s<8;s++) g[(i0+r)*64 + (j0+s)] = acc[r][s];
    }
  }
}

__global__ void k_gramr(const float* __restrict__ Gpart, const float* __restrict__ Spart,
                        float* __restrict__ G, float* __restrict__ S, int nblk){
  int zb = blockIdx.x; int tid = threadIdx.x;
  float a[16];
  #pragma unroll
  for(int e=0;e<16;e++) a[e]=0.f;
  for(int k=0;k<nblk;k++){
    const float* g = Gpart + ((size_t)zb*GNB + k)*4096 + tid*16;
    #pragma unroll
    for(int e=0;e<16;e++) a[e]+=g[e];
  }
  float* go = G + (size_t)zb*4096 + tid*16;
  #pragma unroll
  for(int e=0;e<16;e++) go[e]=a[e];
  if(tid<64){
    float s=0.f;
    for(int k=0;k<nblk;k++) s += Spart[((size_t)zb*GNB + k)*64 + tid];
    S[(size_t)zb*64 + tid]=s;
  }
}

// GN stats from Gram, weights rounded to bf16 (match MFMA arithmetic)
__global__ void k_stats64(const float* __restrict__ W, const float* __restrict__ bias,
                          const float* __restrict__ G, const float* __restrict__ S,
                          float* __restrict__ stat, float Nf){
  __shared__ float rs[256], rq[256];
  int b=blockIdx.x, t=threadIdx.x;
  int o = t&63, sl = t>>6;
  float w[64];
  #pragma unroll
  for(int j2=0;j2<64;j2++) w[j2]=bu2f(f2bu(W[(size_t)o*64+j2]));
  float wl[16];
  #pragma unroll
  for(int r=0;r<16;r++) wl[r]=w[sl*16+r];
  const float* Gr = G + (size_t)b*4096 + (size_t)(sl*16)*64;
  float quad=0.f;
  #pragma unroll
  for(int r=0;r<16;r++){
    const float* gr = Gr + r*64;
    float tt=0.f;
    #pragma unroll
    for(int j2=0;j2<64;j2++) tt += gr[j2]*w[j2];
    quad += wl[r]*tt;
  }
  float dot=0.f;
  #pragma unroll
  for(int j2=0;j2<64;j2++) dot += w[j2]*S[b*64+j2];
  float bo = bias[o];
  float sm = (sl==0)? (dot + Nf*bo) : 0.f;
  float sq = quad + ((sl==0)? (2.f*bo*dot + Nf*bo*bo) : 0.f);
  rs[t]=sm; rq[t]=sq;
  __syncthreads();
  if(t<64){
    float s2 = rs[t]+rs[t+64]+rs[t+128]+rs[t+192];
    float q2 = rq[t]+rq[t+64]+rq[t+128]+rq[t+192];
    for(int off=16;off>0;off>>=1){
      s2 += __shfl_down(s2,off,32);
      q2 += __shfl_down(q2,off,32);
    }
    if((t&31)==0){
      int g=t>>5;
      float invN = 1.f/(Nf*32.f);
      float mean = s2*invN;
      float var = q2*invN - mean*mean;
      stat[b*4+g*2]   = mean;
      stat[b*4+g*2+1] = rsqrtf(fmaxf(var,0.f)+1e-5f);
    }
  }
}

__global__ void k_stats256(const float* __restrict__ W, const float* __restrict__ bias,
                           const float* __restrict__ G, const float* __restrict__ S,
                           float* __restrict__ stat, float Nf){
  __shared__ float red[8];
  int b=blockIdx.x, t=threadIdx.x;
  float w[64];
  #pragma unroll
  for(int j2=0;j2<64;j2++) w[j2]=bu2f(f2bu(W[(size_t)t*64+j2]));
  const float* Gb = G + (size_t)b*4096;
  float quad=0.f;
  #pragma unroll
  for(int i=0;i<64;i++){
    const float* gr = Gb + i*64;
    float tt=0.f;
    #pragma unroll
    for(int j2=0;j2<64;j2++) tt += gr[j2]*w[j2];
    quad += w[i]*tt;
  }
  float dot=0.f;
  #pragma unroll
  for(int j2=0;j2<64;j2++) dot += w[j2]*S[b*64+j2];
  float bo=bias[t];
  float sm = dot + Nf*bo;
  float sq = quad + 2.f*bo*dot + Nf*bo*bo;
  for(int off=32;off>0;off>>=1){
    sm += __shfl_down(sm,off,64);
    sq += __shfl_down(sq,off,64);
  }
  int wid=t>>6;
  if((t&63)==0){ red[wid*2]=sm; red[wid*2+1]=sq; }
  __syncthreads();
  if(t<2){
    float smt = red[t*4+0]+red[t*4+2];
    float sqt = red[t*4+1]+red[t*4+3];
    float invN = 1.f/(Nf*128.f);
    float mean = smt*invN;
    float var = sqt*invN - mean*mean;
    stat[b*4+t*2]   = mean;
    stat[b*4+t*2+1] = rsqrtf(fmaxf(var,0.f)+1e-5f);
  }
}

// MFMA fused layer: x1 = m2w@gelu(GN(m1w@Cb+m1b)) + m2b ; x2 = GN(ww@A+wb);
// A = gelu?(x1+x2). Wave = 64 px, block = 256 px.
__global__ void __launch_bounds__(256) k_fuse(const bf16* __restrict__ Cb,
    bf16* __restrict__ A,
    const float* __restrict__ m1w, const float* __restrict__ m1b,
    const float* __restrict__ mg,  const float* __restrict__ mbt,
    const float* __restrict__ m2w, const float* __restrict__ m2b,
    const float* __restrict__ wwk, const float* __restrict__ wbk,
    const float* __restrict__ ng,  const float* __restrict__ nb,
    const float* __restrict__ tstat, const float* __restrict__ ustat, int last){
  __shared__ unsigned short vlds[4][64][72];
  int tid=threadIdx.x;
  int wid=tid>>6, l=tid&63;
  int m_=l&15, g=l>>4;
  int b=blockIdx.y;
  int p0=blockIdx.x*256 + wid*64;
  const bf16* cbb = Cb + (size_t)b*NPIX*64;
  const bf16* ab  = A  + (size_t)b*NPIX*64;

  s8v af[4][2];
  f32x4 acc[4][4];

  // ---- GEMM1: t = m1w @ Cb + m1b ----
  #pragma unroll
  for(int mt=0;mt<4;mt++){
    #pragma unroll
    for(int kh=0;kh<2;kh++){
      const float* wp = m1w + (size_t)(16*mt+m_)*64 + 32*kh + 8*g;
      s8v f;
      #pragma unroll
      for(int j=0;j<8;j++) f[j]=(short)f2bu(wp[j]);
      af[mt][kh]=f;
    }
    float4 b4 = *(const float4*)(m1b + 16*mt + 4*g);
    #pragma unroll
    for(int nt=0;nt<4;nt++) acc[mt][nt]=f32x4{b4.x,b4.y,b4.z,b4.w};
  }
  #pragma unroll
  for(int nt=0;nt<4;nt++){
    int p = p0 + 16*nt + m_;
    int pc = p<NPIX? p : NPIX-1;
    const s8v* xb = (const s8v*)(cbb + (size_t)pc*64);
    s8v b0 = xb[g], b1 = xb[4+g];
    #pragma unroll
    for(int mt=0;mt<4;mt++){
      acc[mt][nt]=__builtin_amdgcn_mfma_f32_16x16x32_bf16(af[mt][0],b0,acc[mt][nt],0,0,0);
      acc[mt][nt]=__builtin_amdgcn_mfma_f32_16x16x32_bf16(af[mt][1],b1,acc[mt][nt],0,0,0);
    }
  }
  // ---- epilogue1: GN+gelu -> v (wave-private LDS) ----
  {
    float tm0=tstat[b*4],tr0=tstat[b*4+1],tm1=tstat[b*4+2],tr1=tstat[b*4+3];
    #pragma unroll
    for(int mt=0;mt<4;mt++){
      float4 g4 = *(const float4*)(mg  + 16*mt + 4*g);
      float4 t4 = *(const float4*)(mbt + 16*mt + 4*g);
      float mn = (mt<2)? tm0 : tm1;
      float rs = (mt<2)? tr0 : tr1;
      #pragma unroll
      for(int nt=0;nt<4;nt++){
        int pl = 16*nt + m_;
        f32x4 t = acc[mt][nt];
        float v0 = gelu_f((t[0]-mn)*rs*g4.x + t4.x);
        float v1 = gelu_f((t[1]-mn)*rs*g4.y + t4.y);
        float v2 = gelu_f((t[2]-mn)*rs*g4.z + t4.z);
        float v3 = gelu_f((t[3]-mn)*rs*g4.w + t4.w);
        uint2 pk;
        pk.x = (unsigned)f2bu(v0) | ((unsigned)f2bu(v1)<<16);
        pk.y = (unsigned)f2bu(v2) | ((unsigned)f2bu(v3)<<16);
        *(uint2*)&vlds[wid][pl][16*mt+4*g] = pk;
      }
    }
  }
  __syncthreads();
  // ---- GEMM3: u = ww @ A + wb ----
  #pragma unroll
  for(int mt=0;mt<4;mt++){
    #pragma unroll
    for(int kh=0;kh<2;kh++){
      const float* wp = wwk + (size_t)(16*mt+m_)*64 + 32*kh + 8*g;
      s8v f;
      #pragma unroll
      for(int j=0;j<8;j++) f[j]=(short)f2bu(wp[j]);
      af[mt][kh]=f;
    }
    float4 b4 = *(const float4*)(wbk + 16*mt + 4*g);
    #pragma unroll
    for(int nt=0;nt<4;nt++) acc[mt][nt]=f32x4{b4.x,b4.y,b4.z,b4.w};
  }
  #pragma unroll
  for(int nt=0;nt<4;nt++){
    int p = p0 + 16*nt + m_;
    int pc = p<NPIX? p : NPIX-1;
    const s8v* xb = (const s8v*)(ab + (size_t)pc*64);
    s8v b0 = xb[g], b1 = xb[4+g];
    #pragma unroll
    for(int mt=0;mt<4;mt++){
      acc[mt][nt]=__builtin_amdgcn_mfma_f32_16x16x32_bf16(af[mt][0],b0,acc[mt][nt],0,0,0);
      acc[mt][nt]=__builtin_amdgcn_mfma_f32_16x16x32_bf16(af[mt][1],b1,acc[mt][nt],0,0,0);
    }
  }
  // ---- epilogue3: acc = m2b + GN(u) ----
  {
    float um0=ustat[b*4],ur0=ustat[b*4+1],um1=ustat[b*4+2],ur1=ustat[b*4+3];
    #pragma unroll
    for(int mt=0;mt<4;mt++){
      float4 n4 = *(const float4*)(ng  + 16*mt + 4*g);
      float4 nb4= *(const float4*)(nb  + 16*mt + 4*g);
      float4 m24= *(const float4*)(m2b + 16*mt + 4*g);
      float mn = (mt<2)? um0 : um1;
      float rs = (mt<2)? ur0 : ur1;
      #pragma unroll
      for(int nt=0;nt<4;nt++){
        f32x4 u = acc[mt][nt];
        u[0] = m24.x + (u[0]-mn)*rs*n4.x + nb4.x;
        u[1] = m24.y + (u[1]-mn)*rs*n4.y + nb4.y;
        u[2] = m24.z + (u[2]-mn)*rs*n4.z + nb4.z;
        u[3] = m24.w + (u[3]-mn)*rs*n4.w + nb4.w;
        acc[mt][nt]=u;
      }
    }
  }
  // ---- GEMM2: acc += m2w @ v ----
  #pragma unroll
  for(int mt=0;mt<4;mt++){
    #pragma unroll
    for(int kh=0;kh<2;kh++){
      const float* wp = m2w + (size_t)(16*mt+m_)*64 + 32*kh + 8*g;
      s8v f;
      #pragma unroll
      for(int j=0;j<8;j++) f[j]=(short)f2bu(wp[j]);
      af[mt][kh]=f;
    }
  }
  #pragma unroll
  for(int nt=0;nt<4;nt++){
    int pl = 16*nt + m_;
    const s8v* vp = (const s8v*)&vlds[wid][pl][0];
    s8v b0 = vp[g], b1 = vp[4+g];
    #pragma unroll
    for(int mt=0;mt<4;mt++){
      acc[mt][nt]=__builtin_amdgcn_mfma_f32_16x16x32_bf16(af[mt][0],b0,acc[mt][nt],0,0,0);
      acc[mt][nt]=__builtin_amdgcn_mfma_f32_16x16x32_bf16(af[mt][1],b1,acc[mt][nt],0,0,0);
    }
  }
  // ---- final: h = gelu?(x1+x2) -> A ----
  #pragma unroll
  for(int nt=0;nt<4;nt++){
    int p = p0 + 16*nt + m_;
    if(p>=NPIX) continue;
    bf16* dp = A + ((size_t)b*NPIX + p)*64;
    #pragma unroll
    for(int mt=0;mt<4;mt++){
      f32x4 h = acc[mt][nt];
      float h0=h[0],h1=h[1],h2=h[2],h3=h[3];
      if(!last){ h0=gelu_f(h0); h1=gelu_f(h1); h2=gelu_f(h2); h3=gelu_f(h3); }
      uint2 pk;
      pk.x = (unsigned)f2bu(h0) | ((unsigned)f2bu(h1)<<16);
      pk.y = (unsigned)f2bu(h2) | ((unsigned)f2bu(h3)<<16);
      *(uint2*)(dp + 16*mt + 4*g) = pk;
    }
  }
}

// MFMA head: out = q2w @ gelu(GN(q1w@h_crop+q1b)) + q2b
__global__ void __launch_bounds__(256) k_qout(const bf16* __restrict__ A,
    const float* __restrict__ q1w, const float* __restrict__ q1b,
    const float* __restrict__ qg, const float* __restrict__ qbt,
    const float* __restrict__ q2w, const float* __restrict__ q2b,
    const float* __restrict__ qstat, float* __restrict__ out){
  int tid=threadIdx.x;
  int wid=tid>>6, l=tid&63;
  int m_=l&15, g=l>>4;
  int b=blockIdx.y;
  int p0=blockIdx.x*256 + wid*64;
  s8v bfr[4][2];
  #pragma unroll
  for(int nt=0;nt<4;nt++){
    int p = p0 + 16*nt + m_;
    int hh=p/SS, ww2=p-hh*SS;
    size_t gp = (size_t)hh*NN + ww2;
    const s8v* xb = (const s8v*)(A + ((size_t)b*NPIX + gp)*64);
    bfr[nt][0]=xb[g]; bfr[nt][1]=xb[4+g];
  }
  float m0=qstat[b*4],r0=qstat[b*4+1],m1=qstat[b*4+2],r1=qstat[b*4+3];
  float outv[4]={0.f,0.f,0.f,0.f};
  for(int oc=0;oc<4;oc++){
    s8v af[4][2];
    f32x4 acc[4][4];
    #pragma unroll
    for(int mt=0;mt<4;mt++){
      #pragma unroll
      for(int kh=0;kh<2;kh++){
        const float* wp = q1w + (size_t)(64*oc+16*mt+m_)*64 + 32*kh + 8*g;
        s8v f;
        #pragma unroll
        for(int j=0;j<8;j++) f[j]=(short)f2bu(wp[j]);
        af[mt][kh]=f;
      }
      float4 b4 = *(const float4*)(q1b + 64*oc + 16*mt + 4*g);
      #pragma unroll
      for(int nt=0;nt<4;nt++) acc[mt][nt]=f32x4{b4.x,b4.y,b4.z,b4.w};
    }
    #pragma unroll
    for(int nt=0;nt<4;nt++){
      #pragma unroll
      for(int mt=0;mt<4;mt++){
        acc[mt][nt]=__builtin_amdgcn_mfma_f32_16x16x32_bf16(af[mt][0],bfr[nt][0],acc[mt][nt],0,0,0);
        acc[mt][nt]=__builtin_amdgcn_mfma_f32_16x16x32_bf16(af[mt][1],bfr[nt][1],acc[mt][nt],0,0,0);
      }
    }
    float mn = (oc<2)? m0 : m1;
    float rs = (oc<2)? r0 : r1;
    #pragma unroll
    for(int mt=0;mt<4;mt++){
      float4 g4 = *(const float4*)(qg  + 64*oc + 16*mt + 4*g);
      float4 t4 = *(const float4*)(qbt + 64*oc + 16*mt + 4*g);
      float4 w4 = *(const float4*)(q2w + 64*oc + 16*mt + 4*g);
      #pragma unroll
      for(int nt=0;nt<4;nt++){
        f32x4 t = acc[mt][nt];
        outv[nt] += gelu_f((t[0]-mn)*rs*g4.x + t4.x)*w4.x;
        outv[nt] += gelu_f((t[1]-mn)*rs*g4.y + t4.y)*w4.y;
        outv[nt] += gelu_f((t[2]-mn)*rs*g4.z + t4.z)*w4.z;
        outv[nt] += gelu_f((t[3]-mn)*rs*g4.w + t4.w)*w4.w;
      }
    }
  }
  float qb0 = q2b[0];
  #pragma unroll
  for(int nt=0;nt<4;nt++){
    float s = outv[nt];
    s += __shfl_xor(s,16,64);
    s += __shfl_xor(s,32,64);
    if(g==0){
      int p = p0 + 16*nt + m_;
      out[(size_t)b*QPIX + p] = s + qb0;
    }
  }
}

extern "C" void kernel_launch(void* const* d_in, const int* in_sizes, int n_in,
                              void* d_out, int out_size, void* d_ws, size_t ws_size,
                              hipStream_t stream){
  const float* x   = (const float*)d_in[0];
  const float* Wp  = (const float*)d_in[1];
  const float* bp  = (const float*)d_in[2];
  const float* sw1 = (const float*)d_in[3];
  const float* sw2 = (const float*)d_in[4];
  const float* m1w = (const float*)d_in[5];
  const float* m1b = (const float*)d_in[6];
  const float* mg  = (const float*)d_in[7];
  const float* mbt = (const float*)d_in[8];
  const float* m2w = (const float*)d_in[9];
  const float* m2b = (const float*)d_in[10];
  const float* ww  = (const float*)d_in[11];
  const float* wb  = (const float*)d_in[12];
  const float* ng  = (const float*)d_in[13];
  const float* nb  = (const float*)d_in[14];
  const float* q1w = (const float*)d_in[15];
  const float* q1b = (const float*)d_in[16];
  const float* qg  = (const float*)d_in[17];
  const float* qbt = (const float*)d_in[18];
  const float* q2w = (const float*)d_in[19];
  const float* q2b = (const float*)d_in[20];
  float* out = (float*)d_out;

  char* w8 = (char*)d_ws;
  const size_t ACT_B = (size_t)64*BB*NPIX*sizeof(bf16);   // 41,370,624
  bf16*  A    = (bf16*)(w8);
  bf16*  Cb   = (bf16*)(w8 + ACT_B);
  float* SPEC = (float*)(w8 + 2*ACT_B);                    // XW / Y / Gram-partial overlay
  float* XF   = (float*)(w8 + 2*ACT_B + 9879552);
  float* XO   = (float*)(w8 + 2*ACT_B + 9879552 + 1179648);
  float* TB   = (float*)(w8 + 2*ACT_B + 9879552 + 2*1179648);
  char*  g8   = w8 + 2*ACT_B + 9879552 + 2*1179648 + 20992;
  float* Gfin = (float*)g8;
  float* Sfin = Gfin + 16*4096;
  float* TSTAT= (float*)(g8 + (size_t)(32768+512)*2*4);
  float* USTAT= TSTAT + 32;
  float* QSTAT= USTAT + 32;
  float* UxT  = QSTAT + 32;            // 192*64
  float* UyT  = UxT + 12288;           // 192*64
  float* Gpart = SPEC;
  float* Spart = Gpart + (size_t)16*GNB*4096;
  size_t needed = (size_t)(2*ACT_B) + 9879552 + 2*1179648 + 20992
                + (size_t)(32768+512)*2*4 + 3*32*4 + 2*12288*4;
  if(ws_size < needed) return;

  k_tab<<<11,256,0,stream>>>(TB);
  k_pretab<<<dim3(192,2),64,0,stream>>>(Wp, bp, UxT, UyT);
  k_encoder<<<dim3(158,BB),256,0,stream>>>(x, Wp, UxT, UyT, A);

  for(int l=0;l<4;l++){
    const float* sw1l = sw1 + (size_t)l*1179648;
    const float* sw2l = sw2 + (size_t)l*1179648;
    k_dftw<<<402,256,0,stream>>>(A, TB, SPEC);
    k_dfth<<<576,256,0,stream>>>(SPEC, TB, XF);
    k_modemix<<<288,512,0,stream>>>(XF, sw1l, sw2l, XO);
    k_idfth<<<dim3(1608,3),256,0,stream>>>(XO, TB, SPEC);
    k_idftw<<<1608,256,0,stream>>>(SPEC, TB, Cb);
    k_gramp<<<dim3(GNB,BB,2),256,0,stream>>>(Cb, A, Gpart, Spart, NN, NN);
    k_gramr<<<16,256,0,stream>>>(Gpart, Spart, Gfin, Sfin, GNB);
    k_stats64<<<BB,256,0,stream>>>(m1w + (size_t)l*4096, m1b + l*64, Gfin, Sfin, TSTAT, (float)NPIX);
    k_stats64<<<BB,256,0,stream>>>(ww  + (size_t)l*4096, wb  + l*64, Gfin + (size_t)8*4096, Sfin + 8*64, USTAT, (float)NPIX);
    k_fuse<<<dim3(158,BB),256,0,stream>>>(Cb, A,
          m1w + (size_t)l*4096, m1b + l*64, mg + l*64, mbt + l*64,
          m2w + (size_t)l*4096, m2b + l*64,
          ww  + (size_t)l*4096, wb  + l*64, ng + l*64, nb + l*64,
          TSTAT, USTAT, (l==3)?1:0);
  }

  k_gramp<<<dim3(36,BB,1),256,0,stream>>>(A, A, Gpart, Spart, SS, SS);
  k_gramr<<<BB,256,0,stream>>>(Gpart, Spart, Gfin, Sfin, 36);
  k_stats256<<<BB,256,0,stream>>>(q1w, q1b, Gfin, Sfin, QSTAT, (float)QPIX);
  k_qout<<<dim3(144,BB),256,0,stream>>>(A, q1w, q1b, qg, qbt, q2w, q2b, QSTAT, out);
}

// Round 7
// 1597.608 us; speedup vs baseline: 11.4539x; 1.2505x over previous
//
#include <hip/hip_runtime.h>
#include <hip/hip_bf16.h>
#include <math.h>

// FNO2d: B=8, S=192, pad->201x201, C=64, modes 12x12, 4 layers.
// Pixel-major activations [b][p][c] + MFMA conv GEMMs + packed bf16 weights.
// Merged spectral inverse (idfth+idftw), merged gram-reduce+stats, split head.

#define NN 201
#define SS 192
#define NPIX 40401
#define QPIX 36864
#define BB 8
#define GNB 40
#define XWPL 1234944     // 1608*12*64 (re/im plane stride in floats)
#define PI_F 3.14159265358979323846f

typedef __hip_bfloat16 bf16;
typedef __attribute__((ext_vector_type(8))) short s8v;
typedef __attribute__((ext_vector_type(4))) float f32x4;

__device__ __forceinline__ float gelu_f(float x){
  return 0.5f*x*(1.0f+erff(x*0.7071067811865476f));
}
__device__ __forceinline__ float b2f(bf16 v){ return __bfloat162float(v); }
__device__ __forceinline__ bf16  f2b(float v){ return __float2bfloat16(v); }
__device__ __forceinline__ unsigned short f2bu(float x){
  bf16 h = __float2bfloat16(x);
  unsigned short u; __builtin_memcpy(&u,&h,2); return u;
}
__device__ __forceinline__ float bu2f(unsigned short u){
  unsigned int x = ((unsigned int)u)<<16; float f; __builtin_memcpy(&f,&x,4); return f;
}

// tab[k][n]: cos/sin(2*pi*k*n/201), k=0..12, exact mod-201 reduction
__global__ void k_tab(float* __restrict__ tab){
  int t = blockIdx.x*blockDim.x+threadIdx.x;
  if(t>=13*NN) return;
  int k=t/NN, n=t-k*NN;
  int m=(k*n)%NN;
  float ang = (2.0f*PI_F/201.0f)*(float)m;
  tab[2*t]   = cosf(ang);
  tab[2*t+1] = sinf(ang);
}

// Separable encoder tables. grid (192,2), 64 thr.
__global__ void k_pretab(const float* __restrict__ Wp, const float* __restrict__ bp,
                         float* __restrict__ Ux, float* __restrict__ Uy){
  int i = blockIdx.x;
  int ax = blockIdx.y;
  int c = threadIdx.x;
  float g = (float)i*(1.0f/191.0f);
  float acc;
  if(ax==0) acc = bp[c] + g*Wp[64+c];
  else      acc = g*Wp[128+c];
  int cosBase = (ax==0)? 3 : 4;
  int sinBase = (ax==0)? 23 : 24;
  #pragma unroll
  for(int l=0;l<10;l++){
    float f = PI_F*(float)(1<<l);
    float sv,cv;
    sincosf(g*f,&sv,&cv);
    acc += cv*Wp[(cosBase+2*l)*64+c] + sv*Wp[(sinBase+2*l)*64+c];
  }
  float* U = (ax==0)? Ux : Uy;
  U[i*64+c] = acc;
}

// Pack 16 64x64 weight matrices into bf16 MFMA-fragment order.
// bx 0..11: layer l=bx/3, {m1w,m2w,ww}[bx%3]; bx 12..15: q1w oc chunk.
// dst[d]: d = frag*512 + lane*8 + j; frag=mt*2+kh; src row=16*mt+(lane&15), col=32*kh+8*(lane>>4)+j.
__global__ void k_wpack(const float* __restrict__ m1w, const float* __restrict__ m2w,
                        const float* __restrict__ ww,  const float* __restrict__ q1w,
                        unsigned short* __restrict__ WPK){
  int bx = blockIdx.x, tid = threadIdx.x;
  const float* src;
  if(bx<12){
    int l=bx/3, sel=bx-l*3;
    src = (sel==0)? m1w+(size_t)l*4096 : (sel==1)? m2w+(size_t)l*4096 : ww+(size_t)l*4096;
  } else {
    src = q1w + (size_t)(bx-12)*4096;
  }
  unsigned short* dst = WPK + (size_t)bx*4096;
  #pragma unroll
  for(int t=0;t<16;t++){
    int d = tid*16+t;
    int frag=d>>9, lane=(d>>3)&63, j=d&7;
    int mt=frag>>1, kh=frag&1, m_=lane&15, g=lane>>4;
    dst[d] = f2bu(src[(size_t)(16*mt+m_)*64 + 32*kh + 8*g + j]);
  }
}

// Transpose spectral weights for layer into WT[m][comp][io] (contiguous io).
// grid (64, 5, 2): io-tile, col-tile (288 cols = ky*24+kx*2+comp), matrix z.
__global__ void __launch_bounds__(256) k_wtrans(const float* __restrict__ w1,
        const float* __restrict__ w2, float* __restrict__ WT){
  __shared__ float tile[64][65];
  int io0 = blockIdx.x*64;
  int c0  = blockIdx.y*64;
  int z   = blockIdx.z;
  const float* src = (z==0)? w1 : w2;
  int tid = threadIdx.x;
  #pragma unroll
  for(int it=0;it<16;it++){
    int e = tid + 256*it;
    int r = e>>6, c = e&63;
    if(c0+c<288) tile[r][c] = src[(size_t)(io0+r)*288 + c0 + c];
  }
  __syncthreads();
  #pragma unroll
  for(int it=0;it<16;it++){
    int e = tid + 256*it;
    int rp = e>>6, cp = e&63;      // rp: col within tile, cp: io within tile
    int col = c0 + rp;
    if(col<288){
      int ky = col/24, rm = col - ky*24;
      int kx = rm>>1, comp = rm&1;
      int m = z*144 + ky*12 + kx;
      WT[(size_t)m*8192 + comp*4096 + io0 + cp] = tile[cp][rp];
    }
  }
}

// encoder: A[b][p][c] = x*Wp0[c] + Ux[hh][c] + Uy[ww][c]; zeros in pad.
__global__ void k_encoder(const float* __restrict__ x, const float* __restrict__ Wp,
                          const float* __restrict__ Ux, const float* __restrict__ Uy,
                          bf16* __restrict__ A){
  int tid=threadIdx.x;
  int p = blockIdx.x*256+tid;
  if(p>=NPIX) return;
  int b = blockIdx.y;
  uint4* dst = (uint4*)(A + ((size_t)b*NPIX + p)*64);
  int hh=p/NN, ww=p-hh*NN;
  if(hh>=SS || ww>=SS){
    uint4 z = {0,0,0,0};
    #pragma unroll
    for(int i=0;i<8;i++) dst[i]=z;
    return;
  }
  float xv = x[((size_t)b*SS+hh)*SS+ww];
  const float4* ux = (const float4*)(Ux + hh*64);
  const float4* uy = (const float4*)(Uy + ww*64);
  const float4* w0 = (const float4*)Wp;
  #pragma unroll
  for(int i=0;i<8;i++){
    float4 a0 = ux[2*i],   a1 = ux[2*i+1];
    float4 b0 = uy[2*i],   b1 = uy[2*i+1];
    float4 c0 = w0[2*i],   c1 = w0[2*i+1];
    float v0=xv*c0.x+a0.x+b0.x, v1=xv*c0.y+a0.y+b0.y;
    float v2=xv*c0.z+a0.z+b0.z, v3=xv*c0.w+a0.w+b0.w;
    float v4=xv*c1.x+a1.x+b1.x, v5=xv*c1.y+a1.y+b1.y;
    float v6=xv*c1.z+a1.z+b1.z, v7=xv*c1.w+a1.w+b1.w;
    uint4 v;
    v.x = (unsigned)f2bu(v0) | ((unsigned)f2bu(v1)<<16);
    v.y = (unsigned)f2bu(v2) | ((unsigned)f2bu(v3)<<16);
    v.z = (unsigned)f2bu(v4) | ((unsigned)f2bu(v5)<<16);
    v.w = (unsigned)f2bu(v6) | ((unsigned)f2bu(v7)<<16);
    dst[i]=v;
  }
}

// DFT along W. Wave per row R=b*201+h, lane=c. XW[re/im][R][kx][c].
__global__ void __launch_bounds__(256) k_dftw(const bf16* __restrict__ A,
        const float* __restrict__ tab, float* __restrict__ XW){
  __shared__ float2 st[2412];
  int tid=threadIdx.x;
  for(int i=tid;i<2412;i+=256) st[i]=((const float2*)tab)[i];
  __syncthreads();
  int R = blockIdx.x*4 + (tid>>6);
  int l = tid&63;
  const bf16* base = A + ((size_t)R*NN)*64 + l;
  float ar0=0.f;
  float ar[11], ai[11];
  #pragma unroll
  for(int k=0;k<11;k++){ ar[k]=0.f; ai[k]=0.f; }
  for(int w=0;w<NN;w++){
    float a = b2f(base[(size_t)w*64]);
    ar0 += a;
    #pragma unroll
    for(int k=0;k<11;k++){
      float2 cs = st[(k+1)*NN+w];
      ar[k] += a*cs.x;
      ai[k] += a*cs.y;
    }
  }
  float* xre = XW + ((size_t)R*12)*64 + l;
  float* xim = xre + XWPL;
  xre[0]=ar0; xim[0]=0.f;
  #pragma unroll
  for(int k=0;k<11;k++){
    xre[(size_t)(k+1)*64] = ar[k];
    xim[(size_t)(k+1)*64] = -ai[k];
  }
}

// DFT along H: XF[m][b*64+c][{re,im}]
__global__ void k_dfth(const float* __restrict__ XW, const float* __restrict__ tab,
                       float* __restrict__ XF){
  __shared__ float2 st[NN];
  int bx = blockIdx.x;               // 576 = 8*24*3
  int b = bx/72, rem = bx - b*72;
  int j = rem/3, q = rem - (rem/3)*3;
  int tid=threadIdx.x;
  int kx = q*4 + (tid>>6);
  int c = tid&63;
  int k2 = (j<12)? j : 24-j;
  float sgn = (j<12)? -1.0f : 1.0f;
  for(int i=tid;i<NN;i+=256) st[i]=((const float2*)tab)[k2*NN+i];
  __syncthreads();
  const float* re = XW + (((size_t)b*NN)*12 + kx)*64 + c;
  const float* im = re + XWPL;
  float sre=0.f,sim=0.f;
  for(int h=0;h<NN;h++){
    float a = re[(size_t)h*768];
    float b2 = im[(size_t)h*768];
    float2 cs = st[h];
    float cc=cs.x, s2=sgn*cs.y;
    sre += a*cc - b2*s2;
    sim += a*s2 + b2*cc;
  }
  int m = j*12+kx;
  XF[(size_t)m*1024 + (b*64+c)*2]   = sre;
  XF[(size_t)m*1024 + (b*64+c)*2+1] = sim;
}

// per-mode 64x64 complex mix; weights from transposed WT (contiguous)
__global__ void __launch_bounds__(512) k_modemix(const float* __restrict__ XF,
     const float* __restrict__ WT, float* __restrict__ XO){
  __shared__ float sx[1024];
  __shared__ float swr[4096], swi[4096];
  int m=blockIdx.x;
  int tid=threadIdx.x;
  sx[tid]     = XF[(size_t)m*1024+tid];
  sx[tid+512] = XF[(size_t)m*1024+tid+512];
  const float* wr = WT + (size_t)m*8192;
  const float* wi = wr + 4096;
  for(int io=tid;io<4096;io+=512){
    swr[io]=wr[io];
    swi[io]=wi[io];
  }
  __syncthreads();
  int b=tid>>6, o=tid&63;
  const float* xb = sx + b*128;
  float re=0.0f,im=0.0f;
  #pragma unroll 8
  for(int i=0;i<64;i++){
    float a=xb[2*i], b2=xb[2*i+1];
    float c=swr[i*64+o], d=swi[i*64+o];
    re += a*c - b2*d;
    im += a*d + b2*c;
  }
  XO[2*((size_t)m*512+tid)]  =re;
  XO[2*((size_t)m*512+tid)+1]=im;
}

// Merged inverse: per row R, idfth into LDS, then C2R along W. C[b][p][o] bf16.
__global__ void __launch_bounds__(256) k_ispec(const float* __restrict__ XO,
        const float* __restrict__ tab, bf16* __restrict__ C){
  __shared__ float2 st[2412];      // k=0..11 cos/sin rows
  __shared__ float2 yl[12][64];
  __shared__ float2 cs13[13];
  int R=blockIdx.x;
  int b=R/NN, h=R-b*NN;
  int tid=threadIdx.x;
  for(int i=tid;i<2412;i+=256) st[i]=((const float2*)tab)[i];
  if(tid<13) cs13[tid]=((const float2*)tab)[tid*NN+h];
  __syncthreads();
  // phase 1: spectral sum over 24 ky modes -> yl[kx][o]
  #pragma unroll
  for(int it=0;it<3;it++){
    int item = tid + 256*it;
    int kx = item>>6, o = item&63;
    float re=0.f,im=0.f;
    #pragma unroll
    for(int j=0;j<24;j++){
      int k2=(j<12)?j:24-j;
      float sgn=(j<12)?1.0f:-1.0f;
      float2 xo = *(const float2*)(XO + 2*(((size_t)(j*12+kx)*512) + b*64 + o));
      float2 cs = cs13[k2];
      float cc=cs.x, s2=sgn*cs.y;
      re += xo.x*cc - xo.y*s2;
      im += xo.x*s2 + xo.y*cc;
    }
    yl[kx][o] = float2{re,im};
  }
  __syncthreads();
  // phase 2: C2R along W
  int o = tid&63, wq = tid>>6;
  float yr[12], yi[12];
  #pragma unroll
  for(int k=0;k<12;k++){
    float2 v = yl[k][o];
    yr[k]=v.x; yi[k]=v.y;
  }
  int w0 = wq*51;
  int w1 = w0+51; if(w1>NN) w1=NN;
  bf16* cp = C + ((size_t)R*NN)*64 + o;
  for(int w=w0;w<w1;w++){
    float acc = yr[0];
    #pragma unroll
    for(int k=1;k<12;k++){
      float2 cs = st[k*NN+w];
      acc += 2.0f*(yr[k]*cs.x - yi[k]*cs.y);
    }
    cp[(size_t)w*64] = f2b(acc*(1.0f/40401.0f));
  }
}

// Gram partials ([p][c] layout). grid (nblk, BB, nsrc).
__global__ void __launch_bounds__(256) k_gramp(const bf16* __restrict__ s0,
        const bf16* __restrict__ s1, float* __restrict__ Gpart,
        float* __restrict__ Spart, int HR, int WR){
  __shared__ float sx[8704];
  int b = blockIdx.y, blk = blockIdx.x, z = blockIdx.z;
  const bf16* X = (z==0)? s0 : s1;
  int zb = z*BB + b;
  int npix = HR*WR;
  int tid = threadIdx.x;
  int wid = tid>>6, lane = tid&63;
  int i0 = (lane>>3)*8, j0 = (lane&7)*8;
  float acc[8][8];
  #pragma unroll
  for(int r=0;r<8;r++){
    #pragma unroll
    for(int s=0;s<8;s++) acc[r][s]=0.f;
  }
  float cs = 0.f;
  for(int tile=0;tile<8;tile++){
    int rp0 = blk*1024 + tile*128;
    __syncthreads();
    #pragma unroll
    for(int it=0;it<4;it++){
      int chunk = tid + it*256;
      int k = chunk>>3, c0 = (chunk&7)*8;
      int rp = rp0+k;
      float v[8]={0,0,0,0,0,0,0,0};
      if(rp<npix){
        int gp;
        if(WR==NN) gp = rp;
        else { int hh=rp/WR, ww=rp-hh*WR; gp = hh*NN+ww; }
        s8v xv = *(const s8v*)(X + ((size_t)b*NPIX + gp)*64 + c0);
        #pragma unroll
        for(int j=0;j<8;j++) v[j]=bu2f((unsigned short)xv[j]);
      }
      #pragma unroll
      for(int j=0;j<8;j++) sx[k*68+c0+j]=v[j];
    }
    __syncthreads();
    for(int pp=0;pp<32;pp++){
      const float* row = sx + (wid*32+pp)*68;
      cs += row[lane];
      const float4* ri = (const float4*)(row + i0);
      const float4* rj = (const float4*)(row + j0);
      float4 xi0 = ri[0], xi1 = ri[1];
      float4 xj0 = rj[0], xj1 = rj[1];
      float xi[8] = {xi0.x,xi0.y,xi0.z,xi0.w, xi1.x,xi1.y,xi1.z,xi1.w};
      float xj[8] = {xj0.x,xj0.y,xj0.z,xj0.w, xj1.x,xj1.y,xj1.z,xj1.w};
      #pragma unroll
      for(int r=0;r<8;r++){
        #pragma unroll
        for(int s=0;s<8;s++) acc[r][s] += xi[r]*xj[s];
      }
    }
  }
  __syncthreads();
  float* scol = sx + 8320;
  scol[tid] = cs;
  if(wid>=2){
    float* d = sx + (tid-128)*65;
    #pragma unroll
    for(int r=0;r<8;r++){
      #pragma unroll
      for(int s=0;s<8;s++) d[r*8+s]=acc[r][s];
    }
  }
  __syncthreads();
  if(wid<2){
    const float* d = sx + tid*65;
    #pragma unroll
    for(int r=0;r<8;r++){
      #pragma unroll
      for(int s=0;s<8;s++) acc[r][s]+=d[r*8+s];
    }
  }
  if(tid<64){
    float tot = scol[tid]+scol[tid+64]+scol[tid+128]+scol[tid+192];
    Spart[((size_t)zb*GNB + blk)*64 + tid] = tot;
  }
  __syncthreads();
  if(wid==1){
    float* d = sx + (tid-64)*65;
    #pragma unroll
    for(int r=0;r<8;r++){
      #pragma unroll
      for(int s=0;s<8;s++) d[r*8+s]=acc[r][s];
    }
  }
  __syncthreads();
  if(wid==0){
    const float* d = sx + tid*65;
    #pragma unroll
    for(int r=0;r<8;r++){
      #pragma unroll
      for(int s=0;s<8;s++) acc[r][s]+=d[r*8+s];
    }
    float* g = Gpart + ((size_t)zb*GNB + blk)*4096;
    #pragma unroll
    for(int r=0;r<8;r++){
      #pragma unroll
      for(int s=0;s<8;s++) g[(i0+r)*64 + (j0+s)] = acc[r][s];
    }
  }
}

// Merged gram-reduce + GN stats for the layer (grid 16: zb<8 -> m1 stats, zb>=8 -> ww stats).
__global__ void __launch_bounds__(256) k_statsA(const float* __restrict__ Gpart,
        const float* __restrict__ Spart,
        const float* __restrict__ m1wl, const float* __restrict__ m1bl,
        const float* __restrict__ wwl,  const float* __restrict__ wbl,
        float* __restrict__ TSTAT, float* __restrict__ USTAT){
  __shared__ float Gs[4096];
  __shared__ float Ss[64];
  __shared__ float rs[256], rq[256];
  int zb=blockIdx.x, t=threadIdx.x;
  float a[16];
  #pragma unroll
  for(int e=0;e<16;e++) a[e]=0.f;
  for(int k=0;k<GNB;k++){
    const float* g = Gpart + ((size_t)zb*GNB + k)*4096 + t*16;
    #pragma unroll
    for(int e=0;e<16;e++) a[e]+=g[e];
  }
  #pragma unroll
  for(int e=0;e<16;e++) Gs[t*16+e]=a[e];
  if(t<64){
    float s=0.f;
    for(int k=0;k<GNB;k++) s += Spart[((size_t)zb*GNB + k)*64 + t];
    Ss[t]=s;
  }
  __syncthreads();
  const float* W    = (zb<8)? m1wl : wwl;
  const float* bias = (zb<8)? m1bl : wbl;
  float* stat       = (zb<8)? TSTAT : USTAT;
  int b = (zb<8)? zb : zb-8;
  int o = t&63, sl = t>>6;
  float w[64];
  #pragma unroll
  for(int j2=0;j2<64;j2++) w[j2]=bu2f(f2bu(W[(size_t)o*64+j2]));
  const float* Gr = Gs + (size_t)(sl*16)*64;
  float quad=0.f;
  #pragma unroll
  for(int r=0;r<16;r++){
    const float* gr = Gr + r*64;
    float tt=0.f;
    #pragma unroll
    for(int j2=0;j2<64;j2++) tt += gr[j2]*w[j2];
    quad += w[sl*16+r]*tt;
  }
  float dot=0.f;
  #pragma unroll
  for(int j2=0;j2<64;j2++) dot += w[j2]*Ss[j2];
  float bo = bias[o];
  float Nf = (float)NPIX;
  float sm = (sl==0)? (dot + Nf*bo) : 0.f;
  float sq = quad + ((sl==0)? (2.f*bo*dot + Nf*bo*bo) : 0.f);
  rs[t]=sm; rq[t]=sq;
  __syncthreads();
  if(t<64){
    float s2 = rs[t]+rs[t+64]+rs[t+128]+rs[t+192];
    float q2 = rq[t]+rq[t+64]+rq[t+128]+rq[t+192];
    for(int off=16;off>0;off>>=1){
      s2 += __shfl_down(s2,off,32);
      q2 += __shfl_down(q2,off,32);
    }
    if((t&31)==0){
      int g=t>>5;
      float invN = 1.f/(Nf*32.f);
      float mean = s2*invN;
      float var = q2*invN - mean*mean;
      stat[b*4+g*2]   = mean;
      stat[b*4+g*2+1] = rsqrtf(fmaxf(var,0.f)+1e-5f);
    }
  }
}

// Merged gram-reduce + head stats (grid 8).
__global__ void __launch_bounds__(256) k_statsQ(const float* __restrict__ Gpart,
        const float* __restrict__ Spart,
        const float* __restrict__ W, const float* __restrict__ bias,
        float* __restrict__ stat){
  __shared__ float Gs[4096];
  __shared__ float Ss[64];
  __shared__ float red[8];
  int b=blockIdx.x, t=threadIdx.x;
  float a[16];
  #pragma unroll
  for(int e=0;e<16;e++) a[e]=0.f;
  for(int k=0;k<36;k++){
    const float* g = Gpart + ((size_t)b*GNB + k)*4096 + t*16;
    #pragma unroll
    for(int e=0;e<16;e++) a[e]+=g[e];
  }
  #pragma unroll
  for(int e=0;e<16;e++) Gs[t*16+e]=a[e];
  if(t<64){
    float s=0.f;
    for(int k=0;k<36;k++) s += Spart[((size_t)b*GNB + k)*64 + t];
    Ss[t]=s;
  }
  __syncthreads();
  float w[64];
  #pragma unroll
  for(int j2=0;j2<64;j2++) w[j2]=bu2f(f2bu(W[(size_t)t*64+j2]));
  float quad=0.f;
  #pragma unroll
  for(int i=0;i<64;i++){
    const float* gr = Gs + i*64;
    float tt=0.f;
    #pragma unroll
    for(int j2=0;j2<64;j2++) tt += gr[j2]*w[j2];
    quad += w[i]*tt;
  }
  float dot=0.f;
  #pragma unroll
  for(int j2=0;j2<64;j2++) dot += w[j2]*Ss[j2];
  float bo=bias[t];
  float Nf=(float)QPIX;
  float sm = dot + Nf*bo;
  float sq = quad + 2.f*bo*dot + Nf*bo*bo;
  for(int off=32;off>0;off>>=1){
    sm += __shfl_down(sm,off,64);
    sq += __shfl_down(sq,off,64);
  }
  int wid=t>>6;
  if((t&63)==0){ red[wid*2]=sm; red[wid*2+1]=sq; }
  __syncthreads();
  if(t<2){
    float smt = red[t*4+0]+red[t*4+2];
    float sqt = red[t*4+1]+red[t*4+3];
    float invN = 1.f/(Nf*128.f);
    float mean = smt*invN;
    float var = sqt*invN - mean*mean;
    stat[b*4+t*2]   = mean;
    stat[b*4+t*2+1] = rsqrtf(fmaxf(var,0.f)+1e-5f);
  }
}

// MFMA fused layer with packed weights.
__global__ void __launch_bounds__(256) k_fuse(const bf16* __restrict__ Cb,
    bf16* __restrict__ A,
    const unsigned short* __restrict__ wp1, const float* __restrict__ m1b,
    const float* __restrict__ mg,  const float* __restrict__ mbt,
    const unsigned short* __restrict__ wp2, const float* __restrict__ m2b,
    const unsigned short* __restrict__ wpw, const float* __restrict__ wbk,
    const float* __restrict__ ng,  const float* __restrict__ nb,
    const float* __restrict__ tstat, const float* __restrict__ ustat, int last){
  __shared__ unsigned short vlds[4][64][72];
  int tid=threadIdx.x;
  int wid=tid>>6, l=tid&63;
  int m_=l&15, g=l>>4;
  int b=blockIdx.y;
  int p0=blockIdx.x*256 + wid*64;
  const bf16* cbb = Cb + (size_t)b*NPIX*64;
  const bf16* ab  = A  + (size_t)b*NPIX*64;

  s8v af[4][2];
  f32x4 acc[4][4];

  // ---- GEMM1: t = m1w @ Cb + m1b ----
  #pragma unroll
  for(int mt=0;mt<4;mt++){
    #pragma unroll
    for(int kh=0;kh<2;kh++)
      af[mt][kh]=*(const s8v*)(wp1 + (mt*2+kh)*512 + l*8);
    float4 b4 = *(const float4*)(m1b + 16*mt + 4*g);
    #pragma unroll
    for(int nt=0;nt<4;nt++) acc[mt][nt]=f32x4{b4.x,b4.y,b4.z,b4.w};
  }
  #pragma unroll
  for(int nt=0;nt<4;nt++){
    int p = p0 + 16*nt + m_;
    int pc = p<NPIX? p : NPIX-1;
    const s8v* xb = (const s8v*)(cbb + (size_t)pc*64);
    s8v b0 = xb[g], b1 = xb[4+g];
    #pragma unroll
    for(int mt=0;mt<4;mt++){
      acc[mt][nt]=__builtin_amdgcn_mfma_f32_16x16x32_bf16(af[mt][0],b0,acc[mt][nt],0,0,0);
      acc[mt][nt]=__builtin_amdgcn_mfma_f32_16x16x32_bf16(af[mt][1],b1,acc[mt][nt],0,0,0);
    }
  }
  // ---- epilogue1: GN+gelu -> v (wave-private LDS) ----
  {
    float tm0=tstat[b*4],tr0=tstat[b*4+1],tm1=tstat[b*4+2],tr1=tstat[b*4+3];
    #pragma unroll
    for(int mt=0;mt<4;mt++){
      float4 g4 = *(const float4*)(mg  + 16*mt + 4*g);
      float4 t4 = *(const float4*)(mbt + 16*mt + 4*g);
      float mn = (mt<2)? tm0 : tm1;
      float rs = (mt<2)? tr0 : tr1;
      #pragma unroll
      for(int nt=0;nt<4;nt++){
        int pl = 16*nt + m_;
        f32x4 t = acc[mt][nt];
        float v0 = gelu_f((t[0]-mn)*rs*g4.x + t4.x);
        float v1 = gelu_f((t[1]-mn)*rs*g4.y + t4.y);
        float v2 = gelu_f((t[2]-mn)*rs*g4.z + t4.z);
        float v3 = gelu_f((t[3]-mn)*rs*g4.w + t4.w);
        uint2 pk;
        pk.x = (unsigned)f2bu(v0) | ((unsigned)f2bu(v1)<<16);
        pk.y = (unsigned)f2bu(v2) | ((unsigned)f2bu(v3)<<16);
        *(uint2*)&vlds[wid][pl][16*mt+4*g] = pk;
      }
    }
  }
  __syncthreads();
  // ---- GEMM3: u = ww @ A + wb ----
  #pragma unroll
  for(int mt=0;mt<4;mt++){
    #pragma unroll
    for(int kh=0;kh<2;kh++)
      af[mt][kh]=*(const s8v*)(wpw + (mt*2+kh)*512 + l*8);
    float4 b4 = *(const float4*)(wbk + 16*mt + 4*g);
    #pragma unroll
    for(int nt=0;nt<4;nt++) acc[mt][nt]=f32x4{b4.x,b4.y,b4.z,b4.w};
  }
  #pragma unroll
  for(int nt=0;nt<4;nt++){
    int p = p0 + 16*nt + m_;
    int pc = p<NPIX? p : NPIX-1;
    const s8v* xb = (const s8v*)(ab + (size_t)pc*64);
    s8v b0 = xb[g], b1 = xb[4+g];
    #pragma unroll
    for(int mt=0;mt<4;mt++){
      acc[mt][nt]=__builtin_amdgcn_mfma_f32_16x16x32_bf16(af[mt][0],b0,acc[mt][nt],0,0,0);
      acc[mt][nt]=__builtin_amdgcn_mfma_f32_16x16x32_bf16(af[mt][1],b1,acc[mt][nt],0,0,0);
    }
  }
  // ---- epilogue3: acc = m2b + GN(u) ----
  {
    float um0=ustat[b*4],ur0=ustat[b*4+1],um1=ustat[b*4+2],ur1=ustat[b*4+3];
    #pragma unroll
    for(int mt=0;mt<4;mt++){
      float4 n4 = *(const float4*)(ng  + 16*mt + 4*g);
      float4 nb4= *(const float4*)(nb  + 16*mt + 4*g);
      float4 m24= *(const float4*)(m2b + 16*mt + 4*g);
      float mn = (mt<2)? um0 : um1;
      float rs = (mt<2)? ur0 : ur1;
      #pragma unroll
      for(int nt=0;nt<4;nt++){
        f32x4 u = acc[mt][nt];
        u[0] = m24.x + (u[0]-mn)*rs*n4.x + nb4.x;
        u[1] = m24.y + (u[1]-mn)*rs*n4.y + nb4.y;
        u[2] = m24.z + (u[2]-mn)*rs*n4.z + nb4.z;
        u[3] = m24.w + (u[3]-mn)*rs*n4.w + nb4.w;
        acc[mt][nt]=u;
      }
    }
  }
  // ---- GEMM2: acc += m2w @ v ----
  #pragma unroll
  for(int mt=0;mt<4;mt++){
    #pragma unroll
    for(int kh=0;kh<2;kh++)
      af[mt][kh]=*(const s8v*)(wp2 + (mt*2+kh)*512 + l*8);
  }
  #pragma unroll
  for(int nt=0;nt<4;nt++){
    int pl = 16*nt + m_;
    const s8v* vp = (const s8v*)&vlds[wid][pl][0];
    s8v b0 = vp[g], b1 = vp[4+g];
    #pragma unroll
    for(int mt=0;mt<4;mt++){
      acc[mt][nt]=__builtin_amdgcn_mfma_f32_16x16x32_bf16(af[mt][0],b0,acc[mt][nt],0,0,0);
      acc[mt][nt]=__builtin_amdgcn_mfma_f32_16x16x32_bf16(af[mt][1],b1,acc[mt][nt],0,0,0);
    }
  }
  // ---- final: h = gelu?(x1+x2) -> A ----
  #pragma unroll
  for(int nt=0;nt<4;nt++){
    int p = p0 + 16*nt + m_;
    if(p>=NPIX) continue;
    bf16* dp = A + ((size_t)b*NPIX + p)*64;
    #pragma unroll
    for(int mt=0;mt<4;mt++){
      f32x4 h = acc[mt][nt];
      float h0=h[0],h1=h[1],h2=h[2],h3=h[3];
      if(!last){ h0=gelu_f(h0); h1=gelu_f(h1); h2=gelu_f(h2); h3=gelu_f(h3); }
      uint2 pk;
      pk.x = (unsigned)f2bu(h0) | ((unsigned)f2bu(h1)<<16);
      pk.y = (unsigned)f2bu(h2) | ((unsigned)f2bu(h3)<<16);
      *(uint2*)(dp + 16*mt + 4*g) = pk;
    }
  }
}

// Head pass 1 (split by oc chunk): PQ[oc][b][p] = sum over this chunk's 64 channels.
__global__ void __launch_bounds__(256) k_qout1(const bf16* __restrict__ A,
    const unsigned short* __restrict__ qpack, const float* __restrict__ q1b,
    const float* __restrict__ qg, const float* __restrict__ qbt,
    const float* __restrict__ q2w, const float* __restrict__ qstat,
    float* __restrict__ PQ){
  int tid=threadIdx.x;
  int wid=tid>>6, l=tid&63;
  int m_=l&15, g=l>>4;
  int b=blockIdx.y;
  int oc=blockIdx.z;
  int p0=blockIdx.x*256 + wid*64;
  s8v bfr[4][2];
  #pragma unroll
  for(int nt=0;nt<4;nt++){
    int p = p0 + 16*nt + m_;
    int hh=p/SS, ww2=p-hh*SS;
    size_t gp = (size_t)hh*NN + ww2;
    const s8v* xb = (const s8v*)(A + ((size_t)b*NPIX + gp)*64);
    bfr[nt][0]=xb[g]; bfr[nt][1]=xb[4+g];
  }
  const unsigned short* wp = qpack + (size_t)oc*4096;
  s8v af[4][2];
  f32x4 acc[4][4];
  #pragma unroll
  for(int mt=0;mt<4;mt++){
    #pragma unroll
    for(int kh=0;kh<2;kh++)
      af[mt][kh]=*(const s8v*)(wp + (mt*2+kh)*512 + l*8);
    float4 b4 = *(const float4*)(q1b + 64*oc + 16*mt + 4*g);
    #pragma unroll
    for(int nt=0;nt<4;nt++) acc[mt][nt]=f32x4{b4.x,b4.y,b4.z,b4.w};
  }
  #pragma unroll
  for(int nt=0;nt<4;nt++){
    #pragma unroll
    for(int mt=0;mt<4;mt++){
      acc[mt][nt]=__builtin_amdgcn_mfma_f32_16x16x32_bf16(af[mt][0],bfr[nt][0],acc[mt][nt],0,0,0);
      acc[mt][nt]=__builtin_amdgcn_mfma_f32_16x16x32_bf16(af[mt][1],bfr[nt][1],acc[mt][nt],0,0,0);
    }
  }
  float m0=qstat[b*4],r0=qstat[b*4+1],m1=qstat[b*4+2],r1=qstat[b*4+3];
  float mn = (oc<2)? m0 : m1;
  float rs = (oc<2)? r0 : r1;
  float outv[4]={0.f,0.f,0.f,0.f};
  #pragma unroll
  for(int mt=0;mt<4;mt++){
    float4 g4 = *(const float4*)(qg  + 64*oc + 16*mt + 4*g);
    float4 t4 = *(const float4*)(qbt + 64*oc + 16*mt + 4*g);
    float4 w4 = *(const float4*)(q2w + 64*oc + 16*mt + 4*g);
    #pragma unroll
    for(int nt=0;nt<4;nt++){
      f32x4 t = acc[mt][nt];
      outv[nt] += gelu_f((t[0]-mn)*rs*g4.x + t4.x)*w4.x;
      outv[nt] += gelu_f((t[1]-mn)*rs*g4.y + t4.y)*w4.y;
      outv[nt] += gelu_f((t[2]-mn)*rs*g4.z + t4.z)*w4.z;
      outv[nt] += gelu_f((t[3]-mn)*rs*g4.w + t4.w)*w4.w;
    }
  }
  #pragma unroll
  for(int nt=0;nt<4;nt++){
    float s = outv[nt];
    s += __shfl_xor(s,16,64);
    s += __shfl_xor(s,32,64);
    if(g==0){
      int p = p0 + 16*nt + m_;
      PQ[((size_t)oc*BB + b)*QPIX + p] = s;
    }
  }
}

// Head pass 2: out = q2b + sum_oc PQ
__global__ void k_qred(const float* __restrict__ PQ, const float* __restrict__ q2b,
                       float* __restrict__ out){
  int b=blockIdx.y;
  int p=blockIdx.x*256+threadIdx.x;
  float s = q2b[0];
  #pragma unroll
  for(int oc=0;oc<4;oc++) s += PQ[((size_t)oc*BB + b)*QPIX + p];
  out[(size_t)b*QPIX+p]=s;
}

extern "C" void kernel_launch(void* const* d_in, const int* in_sizes, int n_in,
                              void* d_out, int out_size, void* d_ws, size_t ws_size,
                              hipStream_t stream){
  const float* x   = (const float*)d_in[0];
  const float* Wp  = (const float*)d_in[1];
  const float* bp  = (const float*)d_in[2];
  const float* sw1 = (const float*)d_in[3];
  const float* sw2 = (const float*)d_in[4];
  const float* m1w = (const float*)d_in[5];
  const float* m1b = (const float*)d_in[6];
  const float* mg  = (const float*)d_in[7];
  const float* mbt = (const float*)d_in[8];
  const float* m2w = (const float*)d_in[9];
  const float* m2b = (const float*)d_in[10];
  const float* ww  = (const float*)d_in[11];
  const float* wb  = (const float*)d_in[12];
  const float* ng  = (const float*)d_in[13];
  const float* nb  = (const float*)d_in[14];
  const float* q1w = (const float*)d_in[15];
  const float* q1b = (const float*)d_in[16];
  const float* qg  = (const float*)d_in[17];
  const float* qbt = (const float*)d_in[18];
  const float* q2w = (const float*)d_in[19];
  const float* q2b = (const float*)d_in[20];
  float* out = (float*)d_out;

  char* w8 = (char*)d_ws;
  const size_t ACT_B = (size_t)64*BB*NPIX*sizeof(bf16);   // 41,370,624
  bf16*  A    = (bf16*)(w8);
  bf16*  Cb   = (bf16*)(w8 + ACT_B);
  float* SPEC = (float*)(w8 + 2*ACT_B);                    // XW / WT / Gpart / PQ overlays
  float* XF   = (float*)(w8 + 2*ACT_B + 9879552);
  float* XO   = (float*)(w8 + 2*ACT_B + 9879552 + 1179648);
  float* TB   = (float*)(w8 + 2*ACT_B + 9879552 + 2*1179648);
  char*  g8   = w8 + 2*ACT_B + 9879552 + 2*1179648 + 20992;
  float* TSTAT= (float*)g8;
  float* USTAT= TSTAT + 32;
  float* QSTAT= USTAT + 32;
  float* UxT  = QSTAT + 32;                  // 192*64
  float* UyT  = UxT + 12288;                 // 192*64
  unsigned short* WPK = (unsigned short*)(UyT + 12288);   // 16*4096 bf16
  float* Gpart = SPEC;
  float* Spart = Gpart + (size_t)16*GNB*4096;
  float* WT = SPEC;                          // 288*8192 floats = 9.44MB <= 9.88MB
  float* PQ = SPEC;                          // 4*8*36864 floats = 4.7MB
  size_t needed = (size_t)(2*ACT_B) + 9879552 + 2*1179648 + 20992
                + 3*32*4 + 2*12288*4 + 16*4096*2;
  if(ws_size < needed) return;

  k_tab<<<11,256,0,stream>>>(TB);
  k_pretab<<<dim3(192,2),64,0,stream>>>(Wp, bp, UxT, UyT);
  k_wpack<<<16,256,0,stream>>>(m1w, m2w, ww, q1w, WPK);
  k_encoder<<<dim3(158,BB),256,0,stream>>>(x, Wp, UxT, UyT, A);

  for(int l=0;l<4;l++){
    const float* sw1l = sw1 + (size_t)l*1179648;
    const float* sw2l = sw2 + (size_t)l*1179648;
    k_dftw<<<402,256,0,stream>>>(A, TB, SPEC);
    k_dfth<<<576,256,0,stream>>>(SPEC, TB, XF);
    k_wtrans<<<dim3(64,5,2),256,0,stream>>>(sw1l, sw2l, WT);
    k_modemix<<<288,512,0,stream>>>(XF, WT, XO);
    k_ispec<<<1608,256,0,stream>>>(XO, TB, Cb);
    k_gramp<<<dim3(GNB,BB,2),256,0,stream>>>(Cb, A, Gpart, Spart, NN, NN);
    k_statsA<<<16,256,0,stream>>>(Gpart, Spart,
          m1w + (size_t)l*4096, m1b + l*64, ww + (size_t)l*4096, wb + l*64,
          TSTAT, USTAT);
    k_fuse<<<dim3(158,BB),256,0,stream>>>(Cb, A,
          WPK + (size_t)(l*3+0)*4096, m1b + l*64, mg + l*64, mbt + l*64,
          WPK + (size_t)(l*3+1)*4096, m2b + l*64,
          WPK + (size_t)(l*3+2)*4096, wb  + l*64, ng + l*64, nb + l*64,
          TSTAT, USTAT, (l==3)?1:0);
  }

  k_gramp<<<dim3(36,BB,1),256,0,stream>>>(A, A, Gpart, Spart, SS, SS);
  k_statsQ<<<BB,256,0,stream>>>(Gpart, Spart, q1w, q1b, QSTAT);
  k_qout1<<<dim3(144,BB,4),256,0,stream>>>(A, WPK + (size_t)12*4096, q1b,
          qg, qbt, q2w, QSTAT, PQ);
  k_qred<<<dim3(144,BB),256,0,stream>>>(PQ, q2b, out);
}